// Round 8
// baseline (574.595 us; speedup 1.0000x reference)
//
#include <hip/hip_runtime.h>

#define DIN 256
#define HD 64
#define NHEAD 4

static inline int cdiv(long a, long b) { return (int)((a + b - 1) / b); }

typedef __attribute__((ext_vector_type(8))) short bf16x8;
typedef __attribute__((ext_vector_type(4))) float f32x4;

// ---------------- fills ----------------
__global__ __launch_bounds__(256) void k_fill(float* __restrict__ p, float v, int n) {
  int i = blockIdx.x * 256 + threadIdx.x;
  if (i < n) p[i] = v;
}
__global__ __launch_bounds__(256) void k_filli(int* __restrict__ p, int v, int n) {
  int i = blockIdx.x * 256 + threadIdx.x;
  if (i < n) p[i] = v;
}

// ---------------- CSR build ----------------
__global__ __launch_bounds__(256) void k_count(const int* __restrict__ dst,
                                               int* __restrict__ cnt, int E) {
  int i = blockIdx.x * 256 + threadIdx.x;
  if (i < E) atomicAdd(&cnt[dst[i]], 1);
}

__global__ __launch_bounds__(256) void k_bsum(const int* __restrict__ cnt,
                                              int* __restrict__ bsum, int n) {
  __shared__ int sd[256];
  int i = blockIdx.x * 256 + threadIdx.x;
  sd[threadIdx.x] = (i < n) ? cnt[i] : 0;
  __syncthreads();
  for (int o = 128; o > 0; o >>= 1) {
    if (threadIdx.x < o) sd[threadIdx.x] += sd[threadIdx.x + o];
    __syncthreads();
  }
  if (threadIdx.x == 0) bsum[blockIdx.x] = sd[0];
}

__global__ __launch_bounds__(256) void k_bscan(const int* __restrict__ bsum,
                                               int* __restrict__ boff, int B) {
  __shared__ int sd[256];
  int t = threadIdx.x;
  int v = (t < B) ? bsum[t] : 0;
  sd[t] = v;
  __syncthreads();
  for (int o = 1; o < 256; o <<= 1) {
    int x = (t >= o) ? sd[t - o] : 0;
    __syncthreads();
    sd[t] += x;
    __syncthreads();
  }
  if (t < B) boff[t] = sd[t] - v;  // exclusive
}

// rowptr + cursor init + dinv, fused
__global__ __launch_bounds__(256) void k_rowptr(const int* __restrict__ cnt,
                                                const int* __restrict__ boff,
                                                int* __restrict__ row_ptr,
                                                int* __restrict__ cursor,
                                                float* __restrict__ dinv, int n, int total) {
  __shared__ int sd[256];
  int t = threadIdx.x;
  int i = blockIdx.x * 256 + t;
  int v = (i < n) ? cnt[i] : 0;
  sd[t] = v;
  __syncthreads();
  for (int o = 1; o < 256; o <<= 1) {
    int x = (t >= o) ? sd[t - o] : 0;
    __syncthreads();
    sd[t] += x;
    __syncthreads();
  }
  if (i < n) {
    int rp = boff[blockIdx.x] + sd[t] - v;
    row_ptr[i] = rp;
    cursor[i] = rp;
    dinv[i] = rsqrtf((float)v);  // v = degree incl self-loop
  }
  if (i == n - 1) row_ptr[n] = total;
}

__global__ __launch_bounds__(256) void k_csrfill(const int* __restrict__ src,
                                                 const int* __restrict__ dst,
                                                 int* __restrict__ cursor,
                                                 int* __restrict__ csr_src, int E, int n) {
  int e = blockIdx.x * 256 + threadIdx.x;
  if (e < E) {
    int pos = atomicAdd(&cursor[dst[e]], 1);
    csr_src[pos] = src[e];
  } else if (e < E + n) {
    int i = e - E;
    int pos = atomicAdd(&cursor[i], 1);
    csr_src[pos] = i;
  }
}

// ---------------- bf16 helpers ----------------
__device__ __forceinline__ unsigned short f2bf(float f) {  // RNE
  unsigned u = __float_as_uint(f);
  u += 0x7FFFu + ((u >> 16) & 1u);
  return (unsigned short)(u >> 16);
}
__device__ __forceinline__ float bflo(unsigned u) { return __uint_as_float(u << 16); }
__device__ __forceinline__ float bfhi(unsigned u) { return __uint_as_float(u & 0xFFFF0000u); }

// ---------------- MFMA GEMM: c16[n,KOUT](bf16) = A[n,KIN](f32) @ W[KIN,KOUT](f32) ----------------
template <int KIN, int KOUT>
__global__ __launch_bounds__(256, 4) void k_gmfma(const float* __restrict__ A,
                                                  const float* __restrict__ W,
                                                  unsigned short* __restrict__ c16, int n) {
  __shared__ unsigned short As[64][64];  // [row][k, granule-swizzled]
  __shared__ unsigned short Wt[64][64];  // [col][k, granule-swizzled]
  const int tid = threadIdx.x;
  const int m0 = blockIdx.x * 64;
  const int n0 = blockIdx.y * 64;
  const int lane = tid & 63;
  const int wid = tid >> 6;
  const int wm = wid * 16;
  const int fr = lane & 15;
  const int fg = lane >> 4;
  f32x4 acc[4] = {{0.f, 0.f, 0.f, 0.f},
                  {0.f, 0.f, 0.f, 0.f},
                  {0.f, 0.f, 0.f, 0.f},
                  {0.f, 0.f, 0.f, 0.f}};

  for (int k0 = 0; k0 < KIN; k0 += 64) {
    {
      int row = tid >> 3;  // 0..31
      int g = tid & 7;
#pragma unroll
      for (int q = 0; q < 2; ++q, row += 32) {
        int gr = m0 + row;
        gr = gr < n ? gr : n - 1;
        const float* ap = A + (size_t)gr * KIN + k0 + g * 8;
        float4 f0 = *(const float4*)ap;
        float4 f1 = *(const float4*)(ap + 4);
        uint4 pk;
        pk.x = (unsigned)f2bf(f0.x) | ((unsigned)f2bf(f0.y) << 16);
        pk.y = (unsigned)f2bf(f0.z) | ((unsigned)f2bf(f0.w) << 16);
        pk.z = (unsigned)f2bf(f1.x) | ((unsigned)f2bf(f1.y) << 16);
        pk.w = (unsigned)f2bf(f1.z) | ((unsigned)f2bf(f1.w) << 16);
        *(uint4*)&As[row][(g ^ (row & 7)) * 8] = pk;
      }
    }
    {
      int col = tid & 63;
      int kb = (tid >> 6) * 16;  // 0,16,32,48
      unsigned pk[8];
#pragma unroll
      for (int i = 0; i < 8; ++i) {
        float lo = W[(size_t)(k0 + kb + 2 * i) * KOUT + n0 + col];
        float hi = W[(size_t)(k0 + kb + 2 * i + 1) * KOUT + n0 + col];
        pk[i] = (unsigned)f2bf(lo) | ((unsigned)f2bf(hi) << 16);
      }
      int g0 = kb >> 3;
      uint4 w0; w0.x = pk[0]; w0.y = pk[1]; w0.z = pk[2]; w0.w = pk[3];
      uint4 w1; w1.x = pk[4]; w1.y = pk[5]; w1.z = pk[6]; w1.w = pk[7];
      *(uint4*)&Wt[col][((g0) ^ (col & 7)) * 8] = w0;
      *(uint4*)&Wt[col][((g0 + 1) ^ (col & 7)) * 8] = w1;
    }
    __syncthreads();
#pragma unroll
    for (int ks = 0; ks < 2; ++ks) {
      int ga = ks * 4 + fg;
      bf16x8 af = *(const bf16x8*)&As[wm + fr][(ga ^ (fr & 7)) * 8];
#pragma unroll
      for (int nt = 0; nt < 4; ++nt) {
        bf16x8 bfr = *(const bf16x8*)&Wt[nt * 16 + fr][(ga ^ (fr & 7)) * 8];
        acc[nt] = __builtin_amdgcn_mfma_f32_16x16x32_bf16(af, bfr, acc[nt], 0, 0, 0);
      }
    }
    __syncthreads();
  }

#pragma unroll
  for (int nt = 0; nt < 4; ++nt) {
#pragma unroll
    for (int r = 0; r < 4; ++r) {
      int row = m0 + wm + fg * 4 + r;
      if (row < n) {
        c16[(size_t)row * KOUT + n0 + nt * 16 + fr] = f2bf(acc[nt][r]);
      }
    }
  }
}

// ---------------- att dots + feature-tiled relayout ----------------
// reads xg16[n][256]; writes a_s,a_d and XGr[8 planes][n][32]:
// plane tau holds feats {h*64 + tau*8 + j} laid out as [h*8+j] per node.
__global__ __launch_bounds__(256) void k_att16(const unsigned short* __restrict__ xg16,
                                               const float* __restrict__ attS,
                                               const float* __restrict__ attD,
                                               float* __restrict__ a_s,
                                               float* __restrict__ a_d,
                                               unsigned short* __restrict__ xgr, int n) {
  int node = (blockIdx.x * 256 + threadIdx.x) >> 6;
  int lane = threadIdx.x & 63;
  if (node >= n) return;
  int h = lane >> 4, f4 = (lane & 15) * 4;
  uint2 v = *(const uint2*)(xg16 + (size_t)node * 256 + h * 64 + f4);
  // relayout store: tau = f4>>3, within-node idx = h*8 + (f4&7)
  int tau = f4 >> 3;
  *(uint2*)(xgr + (size_t)tau * n * 32 + (size_t)node * 32 + h * 8 + (f4 & 7)) = v;
  float4 s = *(const float4*)(attS + h * 64 + f4);
  float4 d = *(const float4*)(attD + h * 64 + f4);
  float ps = bflo(v.x) * s.x + bfhi(v.x) * s.y + bflo(v.y) * s.z + bfhi(v.y) * s.w;
  float pd = bflo(v.x) * d.x + bfhi(v.x) * d.y + bflo(v.y) * d.z + bfhi(v.y) * d.w;
#pragma unroll
  for (int o = 8; o > 0; o >>= 1) {
    ps += __shfl_xor(ps, o);
    pd += __shfl_xor(pd, o);
  }
  if ((lane & 15) == 0) {
    a_s[node * NHEAD + h] = ps;
    a_d[node * NHEAD + h] = pd;
  }
}

// ---------------- tiled vector GEMM (f32) ----------------
// MODE 1: bias+relu (f32 C)   MODE 2: bias (float2 stores, 8B-aligned C)
template <int KIN, int KOUT, int MODE>
__global__ __launch_bounds__(256, 4) void k_gemm2(const float* __restrict__ A,
                                                  const float* __restrict__ W,
                                                  const float* __restrict__ bias,
                                                  float* __restrict__ C, int n) {
  constexpr int LD = 68;
  __shared__ float As[64][LD];
  __shared__ float Ws[64][LD];
  const int tid = threadIdx.x;
  const int tx = tid & 15;
  const int ty = tid >> 4;
  const int m0 = blockIdx.x * 64;
  const int n0 = blockIdx.y * 64;
  const int lr = tid >> 4;
  const int lc = (tid & 15) * 4;
  float acc[4][4] = {};

  for (int k0 = 0; k0 < KIN; k0 += 64) {
#pragma unroll
    for (int q = 0; q < 4; ++q) {
      int r = lr + q * 16;
      int gr = m0 + r;
      gr = gr < n ? gr : n - 1;
      *(float4*)&As[r][lc] = *(const float4*)(A + (size_t)gr * KIN + k0 + lc);
      *(float4*)&Ws[r][lc] = *(const float4*)(W + (size_t)(k0 + r) * KOUT + n0 + lc);
    }
    __syncthreads();
#pragma unroll 2
    for (int k = 0; k < 64; k += 4) {
      float4 a0 = *(const float4*)&As[ty][k];
      float4 a1 = *(const float4*)&As[ty + 16][k];
      float4 a2 = *(const float4*)&As[ty + 32][k];
      float4 a3 = *(const float4*)&As[ty + 48][k];
      float4 w0 = *(const float4*)&Ws[k + 0][tx * 4];
      float4 w1 = *(const float4*)&Ws[k + 1][tx * 4];
      float4 w2 = *(const float4*)&Ws[k + 2][tx * 4];
      float4 w3 = *(const float4*)&Ws[k + 3][tx * 4];
#define FMA_ROW(i, av)                                                   \
      acc[i][0] = fmaf(av.x, w0.x, fmaf(av.y, w1.x, fmaf(av.z, w2.x, fmaf(av.w, w3.x, acc[i][0])))); \
      acc[i][1] = fmaf(av.x, w0.y, fmaf(av.y, w1.y, fmaf(av.z, w2.y, fmaf(av.w, w3.y, acc[i][1])))); \
      acc[i][2] = fmaf(av.x, w0.z, fmaf(av.y, w1.z, fmaf(av.z, w2.z, fmaf(av.w, w3.z, acc[i][2])))); \
      acc[i][3] = fmaf(av.x, w0.w, fmaf(av.y, w1.w, fmaf(av.z, w2.w, fmaf(av.w, w3.w, acc[i][3]))));
      FMA_ROW(0, a0)
      FMA_ROW(1, a1)
      FMA_ROW(2, a2)
      FMA_ROW(3, a3)
#undef FMA_ROW
    }
    __syncthreads();
  }

  float4 bv = *(const float4*)(bias + n0 + tx * 4);
#pragma unroll
  for (int i = 0; i < 4; ++i) {
    int gr = m0 + ty + 16 * i;
    float4 r;
    r.x = acc[i][0] + bv.x; r.y = acc[i][1] + bv.y;
    r.z = acc[i][2] + bv.z; r.w = acc[i][3] + bv.w;
    if (MODE == 1) {
      r.x = r.x > 0.f ? r.x : 0.f; r.y = r.y > 0.f ? r.y : 0.f;
      r.z = r.z > 0.f ? r.z : 0.f; r.w = r.w > 0.f ? r.w : 0.f;
    }
    if (gr < n) {
      if (MODE == 2) {
        float2 lo; lo.x = r.x; lo.y = r.y;
        float2 hi; hi.x = r.z; hi.y = r.w;
        *(float2*)(C + (size_t)gr * KOUT + n0 + tx * 4) = lo;
        *(float2*)(C + (size_t)gr * KOUT + n0 + tx * 4 + 2) = hi;
      } else {
        *(float4*)(C + (size_t)gr * KOUT + n0 + tx * 4) = r;
      }
    }
  }
}

// ---------------- GCN aggregation, bf16 gather, quarter-wave per edge ----------------
__global__ __launch_bounds__(256) void k_agg16(const unsigned short* __restrict__ P16,
                                               const int* __restrict__ csr_src,
                                               const int* __restrict__ row_ptr,
                                               const float* __restrict__ dinv,
                                               const float* __restrict__ bias,
                                               const float* __restrict__ resid,
                                               float* __restrict__ out, int n) {
  int node = (blockIdx.x * 256 + threadIdx.x) >> 6;
  int lane = threadIdx.x & 63;
  if (node >= n) return;
  int beg = row_ptr[node], end = row_ptr[node + 1];
  int q = lane & 15, qw = lane >> 4;
  float a0 = 0.f, a1 = 0.f, a2 = 0.f, a3 = 0.f;
  for (int i = beg + qw; i < end; i += 4) {
    int s = csr_src[i];  // uniform within quarter
    float d = dinv[s];
    uint2 v = *(const uint2*)(P16 + (size_t)s * HD + q * 4);
    a0 = fmaf(bflo(v.x), d, a0);
    a1 = fmaf(bfhi(v.x), d, a1);
    a2 = fmaf(bflo(v.y), d, a2);
    a3 = fmaf(bfhi(v.y), d, a3);
  }
  a0 += __shfl_xor(a0, 16); a1 += __shfl_xor(a1, 16);
  a2 += __shfl_xor(a2, 16); a3 += __shfl_xor(a3, 16);
  a0 += __shfl_xor(a0, 32); a1 += __shfl_xor(a1, 32);
  a2 += __shfl_xor(a2, 32); a3 += __shfl_xor(a3, 32);
  if (lane < 16) {
    float dn = dinv[node];
    float4 bv = *(const float4*)(bias + q * 4);
    float4 o;
    o.x = a0 * dn + bv.x; o.y = a1 * dn + bv.y;
    o.z = a2 * dn + bv.z; o.w = a3 * dn + bv.w;
    o.x = o.x > 0.f ? o.x : 0.f; o.y = o.y > 0.f ? o.y : 0.f;
    o.z = o.z > 0.f ? o.z : 0.f; o.w = o.w > 0.f ? o.w : 0.f;
    if (resid) {
      float4 rr = *(const float4*)(resid + (size_t)node * HD + q * 4);
      o.x += rr.x; o.y += rr.y; o.z += rr.z; o.w += rr.w;
    }
    *(float4*)(out + (size_t)node * HD + q * 4) = o;
  }
}

// ---------------- GAT kernel A: segment softmax -> normalized bf16 alphas ----------------
__device__ __forceinline__ float leaky(float v) { return v > 0.f ? v : 0.2f * v; }

__global__ __launch_bounds__(256) void k_gatsm(const float* __restrict__ a_s,
                                               const float* __restrict__ a_d,
                                               const int* __restrict__ csr_src,
                                               const int* __restrict__ row_ptr,
                                               float* __restrict__ galpha,   // f32 fallback
                                               uint2* __restrict__ alph16,   // [nE] bf16x4
                                               int n) {
  __shared__ float4 ew[4][128];
  const int wid = threadIdx.x >> 6;
  const int node = (blockIdx.x * 256 + threadIdx.x) >> 6;
  const int lane = threadIdx.x & 63;
  if (node >= n) return;
  const int beg = row_ptr[node], end = row_ptr[node + 1];
  const bool uselds = (end - beg) <= 128;
  float4 ad = ((const float4*)a_d)[node];

  float m0 = -1e30f, m1 = -1e30f, m2 = -1e30f, m3 = -1e30f;
  for (int i = beg + lane; i < end; i += 64) {
    int s = csr_src[i];
    float4 as = ((const float4*)a_s)[s];
    float4 e;
    e.x = leaky(as.x + ad.x); e.y = leaky(as.y + ad.y);
    e.z = leaky(as.z + ad.z); e.w = leaky(as.w + ad.w);
    if (uselds) ew[wid][i - beg] = e; else ((float4*)galpha)[i] = e;
    m0 = fmaxf(m0, e.x); m1 = fmaxf(m1, e.y);
    m2 = fmaxf(m2, e.z); m3 = fmaxf(m3, e.w);
  }
  if (!uselds) __threadfence();
#pragma unroll
  for (int o = 32; o > 0; o >>= 1) {
    m0 = fmaxf(m0, __shfl_xor(m0, o));
    m1 = fmaxf(m1, __shfl_xor(m1, o));
    m2 = fmaxf(m2, __shfl_xor(m2, o));
    m3 = fmaxf(m3, __shfl_xor(m3, o));
  }

  float s0 = 0.f, s1 = 0.f, s2 = 0.f, s3 = 0.f;
  for (int i = beg + lane; i < end; i += 64) {
    float4 e = uselds ? ew[wid][i - beg] : ((const float4*)galpha)[i];
    float4 ex;
    ex.x = expf(e.x - m0); ex.y = expf(e.y - m1);
    ex.z = expf(e.z - m2); ex.w = expf(e.w - m3);
    if (uselds) ew[wid][i - beg] = ex; else ((float4*)galpha)[i] = ex;
    s0 += ex.x; s1 += ex.y; s2 += ex.z; s3 += ex.w;
  }
  if (!uselds) __threadfence();
#pragma unroll
  for (int o = 32; o > 0; o >>= 1) {
    s0 += __shfl_xor(s0, o);
    s1 += __shfl_xor(s1, o);
    s2 += __shfl_xor(s2, o);
    s3 += __shfl_xor(s3, o);
  }
  // fold head-mean 0.25 into normalization
  float r0 = 0.25f / s0, r1 = 0.25f / s1, r2 = 0.25f / s2, r3 = 0.25f / s3;

  for (int i = beg + lane; i < end; i += 64) {
    float4 ex = uselds ? ew[wid][i - beg] : ((const float4*)galpha)[i];
    uint2 w;
    w.x = (unsigned)f2bf(ex.x * r0) | ((unsigned)f2bf(ex.y * r1) << 16);
    w.y = (unsigned)f2bf(ex.z * r2) | ((unsigned)f2bf(ex.w * r3) << 16);
    alph16[i] = w;
  }
}

// ---------------- GAT kernel B: feature-tiled SpMM ----------------
// grid.x = 8 * NB, tile tau = bid / NB (tile-major -> temporal L2 residency of the
// 3.2MB xgr plane). One wave per node; quarter-wave per edge; head-sum via shfl.
__global__ __launch_bounds__(256) void k_spmm(const unsigned short* __restrict__ xgr,
                                              const uint2* __restrict__ alph16,
                                              const int* __restrict__ csr_src,
                                              const int* __restrict__ row_ptr,
                                              const float* __restrict__ bg,
                                              float* __restrict__ hg,   // d_out (8B-aligned)
                                              float* __restrict__ hga,  // aligned ws copy
                                              int n, int NB) {
  const int tau = blockIdx.x / NB;
  const int nb = blockIdx.x % NB;
  const int wid = threadIdx.x >> 6;
  const int lane = threadIdx.x & 63;
  const int node = nb * 4 + wid;
  if (node >= n) return;
  const int q = lane & 15;   // within-quarter: head h=q>>2, feat-pair j0=(q&3)*2
  const int qw = lane >> 4;  // quarter id: edge offset
  const int h = q >> 2;
  const unsigned short* base = xgr + (size_t)tau * n * 32;
  const int beg = row_ptr[node], end = row_ptr[node + 1];

  float a0 = 0.f, a1 = 0.f;
  for (int i = beg + qw; i < end; i += 4) {
    int s = csr_src[i];        // uniform within quarter
    uint2 aw = alph16[i];      // uniform within quarter
    unsigned sel = (h < 2) ? aw.x : aw.y;
    float al = (h & 1) ? bfhi(sel) : bflo(sel);
    unsigned v = *(const unsigned*)(base + (size_t)s * 32 + q * 2);
    a0 = fmaf(bflo(v), al, a0);
    a1 = fmaf(bfhi(v), al, a1);
  }
  // combine quarters (different edges)
  a0 += __shfl_xor(a0, 16); a1 += __shfl_xor(a1, 16);
  a0 += __shfl_xor(a0, 32); a1 += __shfl_xor(a1, 32);
  // combine heads (lanes differing in bits 2,3 of q)
  a0 += __shfl_xor(a0, 4); a1 += __shfl_xor(a1, 4);
  a0 += __shfl_xor(a0, 8); a1 += __shfl_xor(a1, 8);
  if (lane < 4) {
    int f0 = tau * 8 + q * 2;
    float2 o;
    o.x = a0 + bg[f0];
    o.y = a1 + bg[f0 + 1];
    *(float2*)(hg + (size_t)node * HD + f0) = o;
    *(float2*)(hga + (size_t)node * HD + f0) = o;
  }
}

// global feature sum of hg -> gsum[64]
__global__ __launch_bounds__(256) void k_gsum(const float* __restrict__ hg,
                                              float* __restrict__ gsum, int n) {
  __shared__ float red[256];
  int f = threadIdx.x & 63, g = threadIdx.x >> 6;
  float local = 0.f;
  for (int nd = blockIdx.x * 4 + g; nd < n; nd += gridDim.x * 4)
    local += hg[(size_t)nd * HD + f];
  red[threadIdx.x] = local;
  __syncthreads();
  if (threadIdx.x < 64)
    atomicAdd(&gsum[f], red[f] + red[64 + f] + red[128 + f] + red[192 + f]);
}

// tiny classifier head
__global__ __launch_bounds__(64) void k_cls(const float* __restrict__ gsum,
                                            const float* __restrict__ Wc1,
                                            const float* __restrict__ bc1,
                                            const float* __restrict__ Wc2,
                                            const float* __restrict__ bc2,
                                            float* __restrict__ out, int n) {
  __shared__ float hgl[64];
  __shared__ float t1[32];
  int t = threadIdx.x;
  hgl[t] = gsum[t] / (float)n;
  __syncthreads();
  if (t < 32) {
    float a = bc1[t];
#pragma unroll 16
    for (int f = 0; f < 64; ++f) a = fmaf(hgl[f], Wc1[f * 32 + t], a);
    t1[t] = a > 0.f ? a : 0.f;
  }
  __syncthreads();
  if (t < 2) {
    float a = bc2[t];
#pragma unroll
    for (int j = 0; j < 32; ++j) a = fmaf(t1[j], Wc2[j * 2 + t], a);
    out[t] = a;
  }
}

extern "C" void kernel_launch(void* const* d_in, const int* in_sizes, int n_in,
                              void* d_out, int out_size, void* d_ws, size_t ws_size,
                              hipStream_t stream) {
  const float* x = (const float*)d_in[0];
  const int* ei = (const int*)d_in[1];
  const float* W0 = (const float*)d_in[2];
  const float* b0 = (const float*)d_in[3];
  const float* W1 = (const float*)d_in[4];
  const float* b1 = (const float*)d_in[5];
  const float* W2 = (const float*)d_in[6];
  const float* b2 = (const float*)d_in[7];
  const float* Wg = (const float*)d_in[8];
  const float* att_src = (const float*)d_in[9];
  const float* att_dst = (const float*)d_in[10];
  const float* bg = (const float*)d_in[11];
  const float* Wc1 = (const float*)d_in[12];
  const float* bc1 = (const float*)d_in[13];
  const float* Wc2 = (const float*)d_in[14];
  const float* bc2 = (const float*)d_in[15];
  const float* Wr1 = (const float*)d_in[16];
  const float* br1 = (const float*)d_in[17];
  const float* Wr2 = (const float*)d_in[18];
  const float* br2 = (const float*)d_in[19];

  const int n = in_sizes[0] / DIN;  // 50000
  const int E = in_sizes[1] / 2;    // 800000
  const int nE = E + n;
  const int* src = ei;
  const int* dst = ei + E;

  // ---- workspace layout ----
  float* ws = (float*)d_ws;
  size_t off = 0;
  auto alloc = [&](size_t nelems) {
    float* p = ws + off;
    off += (nelems + 63) & ~(size_t)63;
    return p;
  };
  int* CNT = (int*)alloc(n);
  int* BSUM = (int*)alloc(256);
  int* BOFF = (int*)alloc(256);
  int* ROWP = (int*)alloc(n + 1);
  int* CURS = (int*)alloc(n);
  int* CSRS = (int*)alloc(nE);
  float* DINV = alloc(n);
  float* P = alloc((size_t)n * 256);                               // f32 scratch (r1)
  unsigned short* XG16 = (unsigned short*)alloc((size_t)n * 128);  // bf16 xg [n,256]
  unsigned short* XGR = (unsigned short*)alloc((size_t)n * 128);   // bf16 xg, 8-plane relayout
  unsigned short* P16 = (unsigned short*)alloc((size_t)n * 32);    // bf16 P [n,64]
  float* Hb = alloc((size_t)n * HD);                               // hidden h
  float* HG = alloc((size_t)n * HD);                               // aligned copy of hg
  float* ASD = alloc((size_t)n * NHEAD);
  float* ADD = alloc((size_t)n * NHEAD);
  float* GALPHA = alloc((size_t)nE * NHEAD);                       // deg>128 fallback only
  uint2* ALPH16 = (uint2*)alloc((size_t)nE * 2);                   // bf16 alphas [nE][4]
  float* GSUM = alloc(64);
  (void)ws_size;

  float* out = (float*)d_out;
  float* out_cls = out;                       // 2
  float* out_rec = out + 2;                   // n*256
  float* out_hg = out + 2 + (size_t)n * 256;  // n*64

  const int TB = 256;
  const int B = cdiv(n, TB);
  const int GM = cdiv(n, 64);   // GEMM M-tiles
  const int NB = cdiv(n, 4);    // spmm node-blocks per tile

  // ---- CSR build (by dst, self-loops included) ----
  k_filli<<<cdiv(n, TB), TB, 0, stream>>>(CNT, 1, n);  // self loop
  k_count<<<cdiv(E, TB), TB, 0, stream>>>(dst, CNT, E);
  k_bsum<<<B, TB, 0, stream>>>(CNT, BSUM, n);
  k_bscan<<<1, TB, 0, stream>>>(BSUM, BOFF, B);
  k_rowptr<<<B, TB, 0, stream>>>(CNT, BOFF, ROWP, CURS, DINV, n, nE);
  k_csrfill<<<cdiv(nE, TB), TB, 0, stream>>>(src, dst, CURS, CSRS, E, n);

  // ---- GCN layers (MFMA GEMM -> bf16 message gather) ----
  k_gmfma<256, 64><<<dim3(GM, 1), TB, 0, stream>>>(x, W0, P16, n);
  k_agg16<<<cdiv((long)n * 64, TB), TB, 0, stream>>>(P16, CSRS, ROWP, DINV, b0, nullptr, Hb, n);

  k_gmfma<64, 64><<<dim3(GM, 1), TB, 0, stream>>>(Hb, W1, P16, n);
  k_agg16<<<cdiv((long)n * 64, TB), TB, 0, stream>>>(P16, CSRS, ROWP, DINV, b1, Hb, Hb, n);

  k_gmfma<64, 64><<<dim3(GM, 1), TB, 0, stream>>>(Hb, W2, P16, n);
  k_agg16<<<cdiv((long)n * 64, TB), TB, 0, stream>>>(P16, CSRS, ROWP, DINV, b2, Hb, Hb, n);

  // ---- GAT ----
  k_gmfma<64, 256><<<dim3(GM, 4), TB, 0, stream>>>(Hb, Wg, XG16, n);
  k_att16<<<cdiv((long)n * 64, TB), TB, 0, stream>>>(XG16, att_src, att_dst, ASD, ADD, XGR, n);
  k_gatsm<<<cdiv((long)n * 64, TB), TB, 0, stream>>>(ASD, ADD, CSRS, ROWP, GALPHA, ALPH16, n);
  k_spmm<<<NB * 8, TB, 0, stream>>>(XGR, ALPH16, CSRS, ROWP, bg, out_hg, HG, n, NB);

  // ---- global pool + heads (f32 vector GEMMs for precision) ----
  k_fill<<<1, TB, 0, stream>>>(GSUM, 0.f, 64);
  k_gsum<<<512, TB, 0, stream>>>(HG, GSUM, n);
  k_cls<<<1, 64, 0, stream>>>(GSUM, Wc1, bc1, Wc2, bc2, out_cls, n);
  k_gemm2<64, 64, 1><<<dim3(GM, 1), TB, 0, stream>>>(HG, Wr1, br1, P, n);
  k_gemm2<64, 256, 2><<<dim3(GM, 4), TB, 0, stream>>>(P, Wr2, br2, out_rec, n);
}

// Round 9
// 380.983 us; speedup vs baseline: 1.5082x; 1.5082x over previous
//
#include <hip/hip_runtime.h>

#define DIN 256
#define HD 64
#define NHEAD 4

static inline int cdiv(long a, long b) { return (int)((a + b - 1) / b); }

typedef __attribute__((ext_vector_type(8))) short bf16x8;
typedef __attribute__((ext_vector_type(4))) float f32x4;

// ---------------- fills ----------------
__global__ __launch_bounds__(256) void k_filli(int* __restrict__ p, int v, int n) {
  int i = blockIdx.x * 256 + threadIdx.x;
  if (i < n) p[i] = v;
}

// ---------------- CSR build ----------------
__global__ __launch_bounds__(256) void k_count(const int* __restrict__ dst,
                                               int* __restrict__ cnt, int E) {
  int i = blockIdx.x * 256 + threadIdx.x;
  if (i < E) atomicAdd(&cnt[dst[i]], 1);
}

__global__ __launch_bounds__(256) void k_bsum(const int* __restrict__ cnt,
                                              int* __restrict__ bsum, int n) {
  __shared__ int sd[256];
  int i = blockIdx.x * 256 + threadIdx.x;
  sd[threadIdx.x] = (i < n) ? cnt[i] : 0;
  __syncthreads();
  for (int o = 128; o > 0; o >>= 1) {
    if (threadIdx.x < o) sd[threadIdx.x] += sd[threadIdx.x + o];
    __syncthreads();
  }
  if (threadIdx.x == 0) bsum[blockIdx.x] = sd[0];
}

__global__ __launch_bounds__(256) void k_bscan(const int* __restrict__ bsum,
                                               int* __restrict__ boff, int B) {
  __shared__ int sd[256];
  int t = threadIdx.x;
  int v = (t < B) ? bsum[t] : 0;
  sd[t] = v;
  __syncthreads();
  for (int o = 1; o < 256; o <<= 1) {
    int x = (t >= o) ? sd[t - o] : 0;
    __syncthreads();
    sd[t] += x;
    __syncthreads();
  }
  if (t < B) boff[t] = sd[t] - v;  // exclusive
}

// rowptr + cursor init + dinv + GSUM zero, fused
__global__ __launch_bounds__(256) void k_rowptr(const int* __restrict__ cnt,
                                                const int* __restrict__ boff,
                                                int* __restrict__ row_ptr,
                                                int* __restrict__ cursor,
                                                float* __restrict__ dinv,
                                                float* __restrict__ gsum, int n, int total) {
  __shared__ int sd[256];
  int t = threadIdx.x;
  int i = blockIdx.x * 256 + t;
  int v = (i < n) ? cnt[i] : 0;
  sd[t] = v;
  __syncthreads();
  for (int o = 1; o < 256; o <<= 1) {
    int x = (t >= o) ? sd[t - o] : 0;
    __syncthreads();
    sd[t] += x;
    __syncthreads();
  }
  if (i < n) {
    int rp = boff[blockIdx.x] + sd[t] - v;
    row_ptr[i] = rp;
    cursor[i] = rp;
    dinv[i] = rsqrtf((float)v);  // v = degree incl self-loop
  }
  if (i == n - 1) row_ptr[n] = total;
  if (blockIdx.x == 0 && t < 64) gsum[t] = 0.f;
}

__global__ __launch_bounds__(256) void k_csrfill(const int* __restrict__ src,
                                                 const int* __restrict__ dst,
                                                 int* __restrict__ cursor,
                                                 int* __restrict__ csr_src, int E, int n) {
  int e = blockIdx.x * 256 + threadIdx.x;
  if (e < E) {
    int pos = atomicAdd(&cursor[dst[e]], 1);
    csr_src[pos] = src[e];
  } else if (e < E + n) {
    int i = e - E;
    int pos = atomicAdd(&cursor[i], 1);
    csr_src[pos] = i;
  }
}

// ---------------- bf16 helpers ----------------
__device__ __forceinline__ unsigned short f2bf(float f) {  // RNE
  unsigned u = __float_as_uint(f);
  u += 0x7FFFu + ((u >> 16) & 1u);
  return (unsigned short)(u >> 16);
}
__device__ __forceinline__ float bflo(unsigned u) { return __uint_as_float(u << 16); }
__device__ __forceinline__ float bfhi(unsigned u) { return __uint_as_float(u & 0xFFFF0000u); }

// ---------------- MFMA GEMM: c16[n,KOUT](bf16) = A[n,KIN](f32) @ W[KIN,KOUT](f32) ----------------
// ATT=1 (KOUT=256 only): also emit a_s/a_d head-dots from f32 accumulators;
// blockIdx.y is the head (its 64-col tile = the whole head).
template <int KIN, int KOUT, int ATT>
__global__ __launch_bounds__(256, 4) void k_gmfma(const float* __restrict__ A,
                                                  const float* __restrict__ W,
                                                  unsigned short* __restrict__ c16, int n,
                                                  const float* __restrict__ attS,
                                                  const float* __restrict__ attD,
                                                  float* __restrict__ a_s,
                                                  float* __restrict__ a_d) {
  __shared__ unsigned short As[64][64];  // [row][k, granule-swizzled]
  __shared__ unsigned short Wt[64][64];  // [col][k, granule-swizzled]
  const int tid = threadIdx.x;
  const int m0 = blockIdx.x * 64;
  const int n0 = blockIdx.y * 64;
  const int lane = tid & 63;
  const int wid = tid >> 6;
  const int wm = wid * 16;
  const int fr = lane & 15;
  const int fg = lane >> 4;
  f32x4 acc[4] = {{0.f, 0.f, 0.f, 0.f},
                  {0.f, 0.f, 0.f, 0.f},
                  {0.f, 0.f, 0.f, 0.f},
                  {0.f, 0.f, 0.f, 0.f}};

  for (int k0 = 0; k0 < KIN; k0 += 64) {
    {
      int row = tid >> 3;  // 0..31
      int g = tid & 7;
#pragma unroll
      for (int q = 0; q < 2; ++q, row += 32) {
        int gr = m0 + row;
        gr = gr < n ? gr : n - 1;
        const float* ap = A + (size_t)gr * KIN + k0 + g * 8;
        float4 f0 = *(const float4*)ap;
        float4 f1 = *(const float4*)(ap + 4);
        uint4 pk;
        pk.x = (unsigned)f2bf(f0.x) | ((unsigned)f2bf(f0.y) << 16);
        pk.y = (unsigned)f2bf(f0.z) | ((unsigned)f2bf(f0.w) << 16);
        pk.z = (unsigned)f2bf(f1.x) | ((unsigned)f2bf(f1.y) << 16);
        pk.w = (unsigned)f2bf(f1.z) | ((unsigned)f2bf(f1.w) << 16);
        *(uint4*)&As[row][(g ^ (row & 7)) * 8] = pk;
      }
    }
    {
      int col = tid & 63;
      int kb = (tid >> 6) * 16;  // 0,16,32,48
      unsigned pk[8];
#pragma unroll
      for (int i = 0; i < 8; ++i) {
        float lo = W[(size_t)(k0 + kb + 2 * i) * KOUT + n0 + col];
        float hi = W[(size_t)(k0 + kb + 2 * i + 1) * KOUT + n0 + col];
        pk[i] = (unsigned)f2bf(lo) | ((unsigned)f2bf(hi) << 16);
      }
      int g0 = kb >> 3;
      uint4 w0; w0.x = pk[0]; w0.y = pk[1]; w0.z = pk[2]; w0.w = pk[3];
      uint4 w1; w1.x = pk[4]; w1.y = pk[5]; w1.z = pk[6]; w1.w = pk[7];
      *(uint4*)&Wt[col][((g0) ^ (col & 7)) * 8] = w0;
      *(uint4*)&Wt[col][((g0 + 1) ^ (col & 7)) * 8] = w1;
    }
    __syncthreads();
#pragma unroll
    for (int ks = 0; ks < 2; ++ks) {
      int ga = ks * 4 + fg;
      bf16x8 af = *(const bf16x8*)&As[wm + fr][(ga ^ (fr & 7)) * 8];
#pragma unroll
      for (int nt = 0; nt < 4; ++nt) {
        bf16x8 bfr = *(const bf16x8*)&Wt[nt * 16 + fr][(ga ^ (fr & 7)) * 8];
        acc[nt] = __builtin_amdgcn_mfma_f32_16x16x32_bf16(af, bfr, acc[nt], 0, 0, 0);
      }
    }
    __syncthreads();
  }

  // ---- epilogue: bf16 store. D: row = wm + fg*4 + r, col = n0 + nt*16 + fr ----
#pragma unroll
  for (int nt = 0; nt < 4; ++nt) {
#pragma unroll
    for (int r = 0; r < 4; ++r) {
      int row = m0 + wm + fg * 4 + r;
      if (row < n) {
        c16[(size_t)row * KOUT + n0 + nt * 16 + fr] = f2bf(acc[nt][r]);
      }
    }
  }
  if (ATT) {
    float attsv[4], attdv[4];
#pragma unroll
    for (int nt = 0; nt < 4; ++nt) {
      attsv[nt] = attS[n0 + nt * 16 + fr];
      attdv[nt] = attD[n0 + nt * 16 + fr];
    }
#pragma unroll
    for (int r = 0; r < 4; ++r) {
      float ps = acc[0][r] * attsv[0] + acc[1][r] * attsv[1] +
                 acc[2][r] * attsv[2] + acc[3][r] * attsv[3];
      float pd = acc[0][r] * attdv[0] + acc[1][r] * attdv[1] +
                 acc[2][r] * attdv[2] + acc[3][r] * attdv[3];
#pragma unroll
      for (int o = 1; o < 16; o <<= 1) {
        ps += __shfl_xor(ps, o);
        pd += __shfl_xor(pd, o);
      }
      int row = m0 + wm + fg * 4 + r;
      if (fr == 0 && row < n) {
        a_s[row * NHEAD + blockIdx.y] = ps;
        a_d[row * NHEAD + blockIdx.y] = pd;
      }
    }
  }
}

// ---------------- tiled vector GEMM (f32) ----------------
// MODE 1: bias+relu (f32 C)   MODE 2: bias (float2 stores, 8B-aligned C)
template <int KIN, int KOUT, int MODE>
__global__ __launch_bounds__(256, 4) void k_gemm2(const float* __restrict__ A,
                                                  const float* __restrict__ W,
                                                  const float* __restrict__ bias,
                                                  float* __restrict__ C, int n) {
  constexpr int LD = 68;
  __shared__ float As[64][LD];
  __shared__ float Ws[64][LD];
  const int tid = threadIdx.x;
  const int tx = tid & 15;
  const int ty = tid >> 4;
  const int m0 = blockIdx.x * 64;
  const int n0 = blockIdx.y * 64;
  const int lr = tid >> 4;
  const int lc = (tid & 15) * 4;
  float acc[4][4] = {};

  for (int k0 = 0; k0 < KIN; k0 += 64) {
#pragma unroll
    for (int q = 0; q < 4; ++q) {
      int r = lr + q * 16;
      int gr = m0 + r;
      gr = gr < n ? gr : n - 1;
      *(float4*)&As[r][lc] = *(const float4*)(A + (size_t)gr * KIN + k0 + lc);
      *(float4*)&Ws[r][lc] = *(const float4*)(W + (size_t)(k0 + r) * KOUT + n0 + lc);
    }
    __syncthreads();
#pragma unroll 2
    for (int k = 0; k < 64; k += 4) {
      float4 a0 = *(const float4*)&As[ty][k];
      float4 a1 = *(const float4*)&As[ty + 16][k];
      float4 a2 = *(const float4*)&As[ty + 32][k];
      float4 a3 = *(const float4*)&As[ty + 48][k];
      float4 w0 = *(const float4*)&Ws[k + 0][tx * 4];
      float4 w1 = *(const float4*)&Ws[k + 1][tx * 4];
      float4 w2 = *(const float4*)&Ws[k + 2][tx * 4];
      float4 w3 = *(const float4*)&Ws[k + 3][tx * 4];
#define FMA_ROW(i, av)                                                   \
      acc[i][0] = fmaf(av.x, w0.x, fmaf(av.y, w1.x, fmaf(av.z, w2.x, fmaf(av.w, w3.x, acc[i][0])))); \
      acc[i][1] = fmaf(av.x, w0.y, fmaf(av.y, w1.y, fmaf(av.z, w2.y, fmaf(av.w, w3.y, acc[i][1])))); \
      acc[i][2] = fmaf(av.x, w0.z, fmaf(av.y, w1.z, fmaf(av.z, w2.z, fmaf(av.w, w3.z, acc[i][2])))); \
      acc[i][3] = fmaf(av.x, w0.w, fmaf(av.y, w1.w, fmaf(av.z, w2.w, fmaf(av.w, w3.w, acc[i][3]))));
      FMA_ROW(0, a0)
      FMA_ROW(1, a1)
      FMA_ROW(2, a2)
      FMA_ROW(3, a3)
#undef FMA_ROW
    }
    __syncthreads();
  }

  float4 bv = *(const float4*)(bias + n0 + tx * 4);
#pragma unroll
  for (int i = 0; i < 4; ++i) {
    int gr = m0 + ty + 16 * i;
    float4 r;
    r.x = acc[i][0] + bv.x; r.y = acc[i][1] + bv.y;
    r.z = acc[i][2] + bv.z; r.w = acc[i][3] + bv.w;
    if (MODE == 1) {
      r.x = r.x > 0.f ? r.x : 0.f; r.y = r.y > 0.f ? r.y : 0.f;
      r.z = r.z > 0.f ? r.z : 0.f; r.w = r.w > 0.f ? r.w : 0.f;
    }
    if (gr < n) {
      if (MODE == 2) {
        float2 lo; lo.x = r.x; lo.y = r.y;
        float2 hi; hi.x = r.z; hi.y = r.w;
        *(float2*)(C + (size_t)gr * KOUT + n0 + tx * 4) = lo;
        *(float2*)(C + (size_t)gr * KOUT + n0 + tx * 4 + 2) = hi;
      } else {
        *(float4*)(C + (size_t)gr * KOUT + n0 + tx * 4) = r;
      }
    }
  }
}

// ---------------- GCN aggregation, bf16 gather, quarter-wave per edge ----------------
__global__ __launch_bounds__(256) void k_agg16(const unsigned short* __restrict__ P16,
                                               const int* __restrict__ csr_src,
                                               const int* __restrict__ row_ptr,
                                               const float* __restrict__ dinv,
                                               const float* __restrict__ bias,
                                               const float* __restrict__ resid,
                                               float* __restrict__ out, int n) {
  int node = (blockIdx.x * 256 + threadIdx.x) >> 6;
  int lane = threadIdx.x & 63;
  if (node >= n) return;
  int beg = row_ptr[node], end = row_ptr[node + 1];
  int q = lane & 15, qw = lane >> 4;
  float a0 = 0.f, a1 = 0.f, a2 = 0.f, a3 = 0.f;
  for (int i = beg + qw; i < end; i += 4) {
    int s = csr_src[i];  // uniform within quarter
    float d = dinv[s];
    uint2 v = *(const uint2*)(P16 + (size_t)s * HD + q * 4);
    a0 = fmaf(bflo(v.x), d, a0);
    a1 = fmaf(bfhi(v.x), d, a1);
    a2 = fmaf(bflo(v.y), d, a2);
    a3 = fmaf(bfhi(v.y), d, a3);
  }
  a0 += __shfl_xor(a0, 16); a1 += __shfl_xor(a1, 16);
  a2 += __shfl_xor(a2, 16); a3 += __shfl_xor(a3, 16);
  a0 += __shfl_xor(a0, 32); a1 += __shfl_xor(a1, 32);
  a2 += __shfl_xor(a2, 32); a3 += __shfl_xor(a3, 32);
  if (lane < 16) {
    float dn = dinv[node];
    float4 bv = *(const float4*)(bias + q * 4);
    float4 o;
    o.x = a0 * dn + bv.x; o.y = a1 * dn + bv.y;
    o.z = a2 * dn + bv.z; o.w = a3 * dn + bv.w;
    o.x = o.x > 0.f ? o.x : 0.f; o.y = o.y > 0.f ? o.y : 0.f;
    o.z = o.z > 0.f ? o.z : 0.f; o.w = o.w > 0.f ? o.w : 0.f;
    if (resid) {
      float4 rr = *(const float4*)(resid + (size_t)node * HD + q * 4);
      o.x += rr.x; o.y += rr.y; o.z += rr.z; o.w += rr.w;
    }
    *(float4*)(out + (size_t)node * HD + q * 4) = o;
  }
}

// ---------------- GAT: fused segment softmax + bf16 gather ----------------
__device__ __forceinline__ float leaky(float v) { return v > 0.f ? v : 0.2f * v; }

__global__ __launch_bounds__(256) void k_gat(const unsigned short* __restrict__ xg16,
                                             const float* __restrict__ a_s,
                                             const float* __restrict__ a_d,
                                             const int* __restrict__ csr_src,
                                             const int* __restrict__ row_ptr,
                                             float* __restrict__ galpha,  // deg>128 fallback
                                             const float* __restrict__ bg,
                                             float* __restrict__ hg,      // d_out slice (8B-aligned)
                                             float* __restrict__ hga,     // aligned ws copy
                                             int n) {
  __shared__ float4 ew[4][128];
  const int wid = threadIdx.x >> 6;
  const int node = (blockIdx.x * 256 + threadIdx.x) >> 6;
  const int lane = threadIdx.x & 63;
  if (node >= n) return;
  const int beg = row_ptr[node], end = row_ptr[node + 1];
  const bool uselds = (end - beg) <= 128;
  float4 ad = ((const float4*)a_d)[node];

  // P1: logits in registers (uselds: <=2 float4 per lane), lane-local max
  float m0 = -1e30f, m1 = -1e30f, m2 = -1e30f, m3 = -1e30f;
  float4 e0, e1;
  const int i0 = beg + lane, i1 = beg + lane + 64;
  if (uselds) {
    if (i0 < end) {
      int s = csr_src[i0];
      float4 as = ((const float4*)a_s)[s];
      e0.x = leaky(as.x + ad.x); e0.y = leaky(as.y + ad.y);
      e0.z = leaky(as.z + ad.z); e0.w = leaky(as.w + ad.w);
      m0 = e0.x; m1 = e0.y; m2 = e0.z; m3 = e0.w;
    }
    if (i1 < end) {
      int s = csr_src[i1];
      float4 as = ((const float4*)a_s)[s];
      e1.x = leaky(as.x + ad.x); e1.y = leaky(as.y + ad.y);
      e1.z = leaky(as.z + ad.z); e1.w = leaky(as.w + ad.w);
      m0 = fmaxf(m0, e1.x); m1 = fmaxf(m1, e1.y);
      m2 = fmaxf(m2, e1.z); m3 = fmaxf(m3, e1.w);
    }
  } else {
    for (int i = i0; i < end; i += 64) {
      int s = csr_src[i];
      float4 as = ((const float4*)a_s)[s];
      float4 e;
      e.x = leaky(as.x + ad.x); e.y = leaky(as.y + ad.y);
      e.z = leaky(as.z + ad.z); e.w = leaky(as.w + ad.w);
      ((float4*)galpha)[i] = e;
      m0 = fmaxf(m0, e.x); m1 = fmaxf(m1, e.y);
      m2 = fmaxf(m2, e.z); m3 = fmaxf(m3, e.w);
    }
    __threadfence();
  }
#pragma unroll
  for (int o = 32; o > 0; o >>= 1) {
    m0 = fmaxf(m0, __shfl_xor(m0, o));
    m1 = fmaxf(m1, __shfl_xor(m1, o));
    m2 = fmaxf(m2, __shfl_xor(m2, o));
    m3 = fmaxf(m3, __shfl_xor(m3, o));
  }

  // P2: exp + store to LDS (or global fallback) + lane-local sum
  float s0 = 0.f, s1 = 0.f, s2 = 0.f, s3 = 0.f;
  if (uselds) {
    if (i0 < end) {
      float4 ex;
      ex.x = expf(e0.x - m0); ex.y = expf(e0.y - m1);
      ex.z = expf(e0.z - m2); ex.w = expf(e0.w - m3);
      ew[wid][i0 - beg] = ex;
      s0 += ex.x; s1 += ex.y; s2 += ex.z; s3 += ex.w;
    }
    if (i1 < end) {
      float4 ex;
      ex.x = expf(e1.x - m0); ex.y = expf(e1.y - m1);
      ex.z = expf(e1.z - m2); ex.w = expf(e1.w - m3);
      ew[wid][i1 - beg] = ex;
      s0 += ex.x; s1 += ex.y; s2 += ex.z; s3 += ex.w;
    }
  } else {
    for (int i = i0; i < end; i += 64) {
      float4 e = ((const float4*)galpha)[i];
      float4 ex;
      ex.x = expf(e.x - m0); ex.y = expf(e.y - m1);
      ex.z = expf(e.z - m2); ex.w = expf(e.w - m3);
      ((float4*)galpha)[i] = ex;
      s0 += ex.x; s1 += ex.y; s2 += ex.z; s3 += ex.w;
    }
    __threadfence();
  }
#pragma unroll
  for (int o = 32; o > 0; o >>= 1) {
    s0 += __shfl_xor(s0, o);
    s1 += __shfl_xor(s1, o);
    s2 += __shfl_xor(s2, o);
    s3 += __shfl_xor(s3, o);
  }
  float r0 = 0.25f / s0, r1 = 0.25f / s1, r2 = 0.25f / s2, r3 = 0.25f / s3;

  // P3: bf16 gather, 4-edge unroll; per-head alpha read as scalar (no selects)
  const int head = lane >> 4;
  const int fo = (lane & 15) * 4;
  float rh = head == 0 ? r0 : head == 1 ? r1 : head == 2 ? r2 : r3;
  float aA0 = 0.f, aA1 = 0.f, aA2 = 0.f, aA3 = 0.f;
  float aB0 = 0.f, aB1 = 0.f, aB2 = 0.f, aB3 = 0.f;
  float aC0 = 0.f, aC1 = 0.f, aC2 = 0.f, aC3 = 0.f;
  float aD0 = 0.f, aD1 = 0.f, aD2 = 0.f, aD3 = 0.f;

#define P3_BODY(ALPHA_AT)                                                        \
  {                                                                              \
    int i = beg;                                                                 \
    for (; i + 4 <= end; i += 4) {                                               \
      int sA = csr_src[i], sB = csr_src[i + 1];                                  \
      int sC = csr_src[i + 2], sD = csr_src[i + 3];                              \
      float alA = ALPHA_AT(i), alB = ALPHA_AT(i + 1);                            \
      float alC = ALPHA_AT(i + 2), alD = ALPHA_AT(i + 3);                        \
      uint2 vA = *(const uint2*)(xg16 + (size_t)sA * 256 + lane * 4);            \
      uint2 vB = *(const uint2*)(xg16 + (size_t)sB * 256 + lane * 4);            \
      uint2 vC = *(const uint2*)(xg16 + (size_t)sC * 256 + lane * 4);            \
      uint2 vD = *(const uint2*)(xg16 + (size_t)sD * 256 + lane * 4);            \
      aA0 = fmaf(bflo(vA.x), alA, aA0); aA1 = fmaf(bfhi(vA.x), alA, aA1);        \
      aA2 = fmaf(bflo(vA.y), alA, aA2); aA3 = fmaf(bfhi(vA.y), alA, aA3);        \
      aB0 = fmaf(bflo(vB.x), alB, aB0); aB1 = fmaf(bfhi(vB.x), alB, aB1);        \
      aB2 = fmaf(bflo(vB.y), alB, aB2); aB3 = fmaf(bfhi(vB.y), alB, aB3);        \
      aC0 = fmaf(bflo(vC.x), alC, aC0); aC1 = fmaf(bfhi(vC.x), alC, aC1);        \
      aC2 = fmaf(bflo(vC.y), alC, aC2); aC3 = fmaf(bfhi(vC.y), alC, aC3);        \
      aD0 = fmaf(bflo(vD.x), alD, aD0); aD1 = fmaf(bfhi(vD.x), alD, aD1);        \
      aD2 = fmaf(bflo(vD.y), alD, aD2); aD3 = fmaf(bfhi(vD.y), alD, aD3);        \
    }                                                                            \
    for (; i < end; ++i) {                                                       \
      int s = csr_src[i];                                                        \
      float al = ALPHA_AT(i);                                                    \
      uint2 v = *(const uint2*)(xg16 + (size_t)s * 256 + lane * 4);              \
      aA0 = fmaf(bflo(v.x), al, aA0); aA1 = fmaf(bfhi(v.x), al, aA1);            \
      aA2 = fmaf(bflo(v.y), al, aA2); aA3 = fmaf(bfhi(v.y), al, aA3);            \
    }                                                                            \
  }

  if (uselds) {
    const float* ap = (const float*)&ew[wid][0];
#define AL_LDS(idx) ap[((idx) - beg) * 4 + head]
    P3_BODY(AL_LDS)
#undef AL_LDS
  } else {
#define AL_GBL(idx) galpha[(size_t)(idx) * 4 + head]
    P3_BODY(AL_GBL)
#undef AL_GBL
  }
#undef P3_BODY

  float t0 = (aA0 + aB0 + aC0 + aD0) * rh;
  float t1 = (aA1 + aB1 + aC1 + aD1) * rh;
  float t2 = (aA2 + aB2 + aC2 + aD2) * rh;
  float t3 = (aA3 + aB3 + aC3 + aD3) * rh;
  // combine heads: groups of 16 lanes hold heads 0..3 for the same feats
  t0 += __shfl_xor(t0, 16); t1 += __shfl_xor(t1, 16);
  t2 += __shfl_xor(t2, 16); t3 += __shfl_xor(t3, 16);
  t0 += __shfl_xor(t0, 32); t1 += __shfl_xor(t1, 32);
  t2 += __shfl_xor(t2, 32); t3 += __shfl_xor(t3, 32);
  if (lane < 16) {
    float4 o;
    o.x = t0 + bg[fo]; o.y = t1 + bg[fo + 1];
    o.z = t2 + bg[fo + 2]; o.w = t3 + bg[fo + 3];
    *(float4*)(hga + (size_t)node * HD + fo) = o;
    float2 lo; lo.x = o.x; lo.y = o.y;
    float2 hi; hi.x = o.z; hi.y = o.w;
    *(float2*)(hg + (size_t)node * HD + fo) = lo;
    *(float2*)(hg + (size_t)node * HD + fo + 2) = hi;
  }
}

// global feature sum of hg -> gsum[64]
__global__ __launch_bounds__(256) void k_gsum(const float* __restrict__ hg,
                                              float* __restrict__ gsum, int n) {
  __shared__ float red[256];
  int f = threadIdx.x & 63, g = threadIdx.x >> 6;
  float local = 0.f;
  for (int nd = blockIdx.x * 4 + g; nd < n; nd += gridDim.x * 4)
    local += hg[(size_t)nd * HD + f];
  red[threadIdx.x] = local;
  __syncthreads();
  if (threadIdx.x < 64)
    atomicAdd(&gsum[f], red[f] + red[64 + f] + red[128 + f] + red[192 + f]);
}

// tiny classifier head
__global__ __launch_bounds__(64) void k_cls(const float* __restrict__ gsum,
                                            const float* __restrict__ Wc1,
                                            const float* __restrict__ bc1,
                                            const float* __restrict__ Wc2,
                                            const float* __restrict__ bc2,
                                            float* __restrict__ out, int n) {
  __shared__ float hgl[64];
  __shared__ float t1[32];
  int t = threadIdx.x;
  hgl[t] = gsum[t] / (float)n;
  __syncthreads();
  if (t < 32) {
    float a = bc1[t];
#pragma unroll 16
    for (int f = 0; f < 64; ++f) a = fmaf(hgl[f], Wc1[f * 32 + t], a);
    t1[t] = a > 0.f ? a : 0.f;
  }
  __syncthreads();
  if (t < 2) {
    float a = bc2[t];
#pragma unroll
    for (int j = 0; j < 32; ++j) a = fmaf(t1[j], Wc2[j * 2 + t], a);
    out[t] = a;
  }
}

extern "C" void kernel_launch(void* const* d_in, const int* in_sizes, int n_in,
                              void* d_out, int out_size, void* d_ws, size_t ws_size,
                              hipStream_t stream) {
  const float* x = (const float*)d_in[0];
  const int* ei = (const int*)d_in[1];
  const float* W0 = (const float*)d_in[2];
  const float* b0 = (const float*)d_in[3];
  const float* W1 = (const float*)d_in[4];
  const float* b1 = (const float*)d_in[5];
  const float* W2 = (const float*)d_in[6];
  const float* b2 = (const float*)d_in[7];
  const float* Wg = (const float*)d_in[8];
  const float* att_src = (const float*)d_in[9];
  const float* att_dst = (const float*)d_in[10];
  const float* bg = (const float*)d_in[11];
  const float* Wc1 = (const float*)d_in[12];
  const float* bc1 = (const float*)d_in[13];
  const float* Wc2 = (const float*)d_in[14];
  const float* bc2 = (const float*)d_in[15];
  const float* Wr1 = (const float*)d_in[16];
  const float* br1 = (const float*)d_in[17];
  const float* Wr2 = (const float*)d_in[18];
  const float* br2 = (const float*)d_in[19];

  const int n = in_sizes[0] / DIN;  // 50000
  const int E = in_sizes[1] / 2;    // 800000
  const int nE = E + n;
  const int* src = ei;
  const int* dst = ei + E;

  // ---- workspace layout ----
  float* ws = (float*)d_ws;
  size_t off = 0;
  auto alloc = [&](size_t nelems) {
    float* p = ws + off;
    off += (nelems + 63) & ~(size_t)63;
    return p;
  };
  int* CNT = (int*)alloc(n);
  int* BSUM = (int*)alloc(256);
  int* BOFF = (int*)alloc(256);
  int* ROWP = (int*)alloc(n + 1);
  int* CURS = (int*)alloc(n);
  int* CSRS = (int*)alloc(nE);
  float* DINV = alloc(n);
  float* P = alloc((size_t)n * 256);                               // f32 scratch (r1)
  unsigned short* XG16 = (unsigned short*)alloc((size_t)n * 128);  // bf16 xg [n,256]
  unsigned short* P16 = (unsigned short*)alloc((size_t)n * 32);    // bf16 P [n,64]
  float* Hb = alloc((size_t)n * HD);                               // hidden h
  float* HG = alloc((size_t)n * HD);                               // aligned copy of hg
  float* ASD = alloc((size_t)n * NHEAD);
  float* ADD = alloc((size_t)n * NHEAD);
  float* GALPHA = alloc((size_t)nE * NHEAD);                       // deg>128 fallback only
  float* GSUM = alloc(64);
  (void)ws_size;

  float* out = (float*)d_out;
  float* out_cls = out;                       // 2
  float* out_rec = out + 2;                   // n*256
  float* out_hg = out + 2 + (size_t)n * 256;  // n*64

  const int TB = 256;
  const int B = cdiv(n, TB);
  const int GM = cdiv(n, 64);  // GEMM M-tiles

  // ---- CSR build (by dst, self-loops included) ----
  k_filli<<<cdiv(n, TB), TB, 0, stream>>>(CNT, 1, n);  // self loop
  k_count<<<cdiv(E, TB), TB, 0, stream>>>(dst, CNT, E);
  k_bsum<<<B, TB, 0, stream>>>(CNT, BSUM, n);
  k_bscan<<<1, TB, 0, stream>>>(BSUM, BOFF, B);
  k_rowptr<<<B, TB, 0, stream>>>(CNT, BOFF, ROWP, CURS, DINV, GSUM, n, nE);
  k_csrfill<<<cdiv(nE, TB), TB, 0, stream>>>(src, dst, CURS, CSRS, E, n);

  // ---- GCN layers (MFMA GEMM -> bf16 message gather) ----
  k_gmfma<256, 64, 0><<<dim3(GM, 1), TB, 0, stream>>>(x, W0, P16, n,
                                                      nullptr, nullptr, nullptr, nullptr);
  k_agg16<<<cdiv((long)n * 64, TB), TB, 0, stream>>>(P16, CSRS, ROWP, DINV, b0, nullptr, Hb, n);

  k_gmfma<64, 64, 0><<<dim3(GM, 1), TB, 0, stream>>>(Hb, W1, P16, n,
                                                     nullptr, nullptr, nullptr, nullptr);
  k_agg16<<<cdiv((long)n * 64, TB), TB, 0, stream>>>(P16, CSRS, ROWP, DINV, b1, Hb, Hb, n);

  k_gmfma<64, 64, 0><<<dim3(GM, 1), TB, 0, stream>>>(Hb, W2, P16, n,
                                                     nullptr, nullptr, nullptr, nullptr);
  k_agg16<<<cdiv((long)n * 64, TB), TB, 0, stream>>>(P16, CSRS, ROWP, DINV, b2, Hb, Hb, n);

  // ---- GAT (att dots fused into MFMA epilogue) ----
  k_gmfma<64, 256, 1><<<dim3(GM, 4), TB, 0, stream>>>(Hb, Wg, XG16, n,
                                                      att_src, att_dst, ASD, ADD);
  k_gat<<<cdiv((long)n * 64, TB), TB, 0, stream>>>(XG16, ASD, ADD, CSRS, ROWP, GALPHA, bg,
                                                   out_hg, HG, n);

  // ---- global pool + heads (f32 vector GEMMs for precision) ----
  k_gsum<<<512, TB, 0, stream>>>(HG, GSUM, n);
  k_cls<<<1, 64, 0, stream>>>(GSUM, Wc1, bc1, Wc2, bc2, out_cls, n);
  k_gemm2<64, 64, 1><<<dim3(GM, 1), TB, 0, stream>>>(HG, Wr1, br1, P, n);
  k_gemm2<64, 256, 2><<<dim3(GM, 4), TB, 0, stream>>>(P, Wr2, br2, out_rec, n);
}

// Round 10
// 351.987 us; speedup vs baseline: 1.6324x; 1.0824x over previous
//
#include <hip/hip_runtime.h>

#define DIN 256
#define HD 64
#define NHEAD 4

static inline int cdiv(long a, long b) { return (int)((a + b - 1) / b); }

typedef __attribute__((ext_vector_type(8))) short bf16x8;
typedef __attribute__((ext_vector_type(4))) float f32x4;

// ---------------- fills ----------------
__global__ __launch_bounds__(256) void k_filli(int* __restrict__ p, int v, int n) {
  int i = blockIdx.x * 256 + threadIdx.x;
  if (i < n) p[i] = v;
}

// ---------------- CSR build ----------------
__global__ __launch_bounds__(256) void k_count(const int* __restrict__ dst,
                                               int* __restrict__ cnt, int E) {
  int i = blockIdx.x * 256 + threadIdx.x;
  if (i < E) atomicAdd(&cnt[dst[i]], 1);
}

__global__ __launch_bounds__(256) void k_bsum(const int* __restrict__ cnt,
                                              int* __restrict__ bsum, int n) {
  __shared__ int sd[256];
  int i = blockIdx.x * 256 + threadIdx.x;
  sd[threadIdx.x] = (i < n) ? cnt[i] : 0;
  __syncthreads();
  for (int o = 128; o > 0; o >>= 1) {
    if (threadIdx.x < o) sd[threadIdx.x] += sd[threadIdx.x + o];
    __syncthreads();
  }
  if (threadIdx.x == 0) bsum[blockIdx.x] = sd[0];
}

__global__ __launch_bounds__(256) void k_bscan(const int* __restrict__ bsum,
                                               int* __restrict__ boff, int B) {
  __shared__ int sd[256];
  int t = threadIdx.x;
  int v = (t < B) ? bsum[t] : 0;
  sd[t] = v;
  __syncthreads();
  for (int o = 1; o < 256; o <<= 1) {
    int x = (t >= o) ? sd[t - o] : 0;
    __syncthreads();
    sd[t] += x;
    __syncthreads();
  }
  if (t < B) boff[t] = sd[t] - v;  // exclusive
}

// rowptr + cursor init + dinv + GSUM zero, fused
__global__ __launch_bounds__(256) void k_rowptr(const int* __restrict__ cnt,
                                                const int* __restrict__ boff,
                                                int* __restrict__ row_ptr,
                                                int* __restrict__ cursor,
                                                float* __restrict__ dinv,
                                                float* __restrict__ gsum, int n, int total) {
  __shared__ int sd[256];
  int t = threadIdx.x;
  int i = blockIdx.x * 256 + t;
  int v = (i < n) ? cnt[i] : 0;
  sd[t] = v;
  __syncthreads();
  for (int o = 1; o < 256; o <<= 1) {
    int x = (t >= o) ? sd[t - o] : 0;
    __syncthreads();
    sd[t] += x;
    __syncthreads();
  }
  if (i < n) {
    int rp = boff[blockIdx.x] + sd[t] - v;
    row_ptr[i] = rp;
    cursor[i] = rp;
    dinv[i] = rsqrtf((float)v);  // v = degree incl self-loop
  }
  if (i == n - 1) row_ptr[n] = total;
  if (blockIdx.x == 0 && t < 64) gsum[t] = 0.f;
}

__global__ __launch_bounds__(256) void k_csrfill(const int* __restrict__ src,
                                                 const int* __restrict__ dst,
                                                 int* __restrict__ cursor,
                                                 int* __restrict__ csr_src, int E, int n) {
  int e = blockIdx.x * 256 + threadIdx.x;
  if (e < E) {
    int pos = atomicAdd(&cursor[dst[e]], 1);
    csr_src[pos] = src[e];
  } else if (e < E + n) {
    int i = e - E;
    int pos = atomicAdd(&cursor[i], 1);
    csr_src[pos] = i;
  }
}

// ---------------- bf16 helpers ----------------
__device__ __forceinline__ unsigned short f2bf(float f) {  // RNE
  unsigned u = __float_as_uint(f);
  u += 0x7FFFu + ((u >> 16) & 1u);
  return (unsigned short)(u >> 16);
}
__device__ __forceinline__ float bflo(unsigned u) { return __uint_as_float(u << 16); }
__device__ __forceinline__ float bfhi(unsigned u) { return __uint_as_float(u & 0xFFFF0000u); }

// ---------------- MFMA GEMM: out = A[n,KIN](f32) @ W[KIN,KOUT](f32) ----------------
// ATT=1 (KOUT=256): also emit a_s/a_d head-dots (blockIdx.y = head).
// EPI=0: bf16 store to c16   EPI=1: f32 bias+relu store to Cf   EPI=2: f32 bias store to Cf
template <int KIN, int KOUT, int ATT, int EPI>
__global__ __launch_bounds__(256, 4) void k_gmfma(const float* __restrict__ A,
                                                  const float* __restrict__ W,
                                                  unsigned short* __restrict__ c16, int n,
                                                  const float* __restrict__ attS,
                                                  const float* __restrict__ attD,
                                                  float* __restrict__ a_s,
                                                  float* __restrict__ a_d,
                                                  const float* __restrict__ bias,
                                                  float* __restrict__ Cf) {
  __shared__ unsigned short As[64][64];  // [row][k, granule-swizzled]
  __shared__ unsigned short Wt[64][64];  // [col][k, granule-swizzled]
  const int tid = threadIdx.x;
  const int m0 = blockIdx.x * 64;
  const int n0 = blockIdx.y * 64;
  const int lane = tid & 63;
  const int wid = tid >> 6;
  const int wm = wid * 16;
  const int fr = lane & 15;
  const int fg = lane >> 4;
  f32x4 acc[4] = {{0.f, 0.f, 0.f, 0.f},
                  {0.f, 0.f, 0.f, 0.f},
                  {0.f, 0.f, 0.f, 0.f},
                  {0.f, 0.f, 0.f, 0.f}};

  for (int k0 = 0; k0 < KIN; k0 += 64) {
    {
      int row = tid >> 3;  // 0..31
      int g = tid & 7;
#pragma unroll
      for (int q = 0; q < 2; ++q, row += 32) {
        int gr = m0 + row;
        gr = gr < n ? gr : n - 1;
        const float* ap = A + (size_t)gr * KIN + k0 + g * 8;
        float4 f0 = *(const float4*)ap;
        float4 f1 = *(const float4*)(ap + 4);
        uint4 pk;
        pk.x = (unsigned)f2bf(f0.x) | ((unsigned)f2bf(f0.y) << 16);
        pk.y = (unsigned)f2bf(f0.z) | ((unsigned)f2bf(f0.w) << 16);
        pk.z = (unsigned)f2bf(f1.x) | ((unsigned)f2bf(f1.y) << 16);
        pk.w = (unsigned)f2bf(f1.z) | ((unsigned)f2bf(f1.w) << 16);
        *(uint4*)&As[row][(g ^ (row & 7)) * 8] = pk;
      }
    }
    {
      int col = tid & 63;
      int kb = (tid >> 6) * 16;  // 0,16,32,48
      unsigned pk[8];
#pragma unroll
      for (int i = 0; i < 8; ++i) {
        float lo = W[(size_t)(k0 + kb + 2 * i) * KOUT + n0 + col];
        float hi = W[(size_t)(k0 + kb + 2 * i + 1) * KOUT + n0 + col];
        pk[i] = (unsigned)f2bf(lo) | ((unsigned)f2bf(hi) << 16);
      }
      int g0 = kb >> 3;
      uint4 w0; w0.x = pk[0]; w0.y = pk[1]; w0.z = pk[2]; w0.w = pk[3];
      uint4 w1; w1.x = pk[4]; w1.y = pk[5]; w1.z = pk[6]; w1.w = pk[7];
      *(uint4*)&Wt[col][((g0) ^ (col & 7)) * 8] = w0;
      *(uint4*)&Wt[col][((g0 + 1) ^ (col & 7)) * 8] = w1;
    }
    __syncthreads();
#pragma unroll
    for (int ks = 0; ks < 2; ++ks) {
      int ga = ks * 4 + fg;
      bf16x8 af = *(const bf16x8*)&As[wm + fr][(ga ^ (fr & 7)) * 8];
#pragma unroll
      for (int nt = 0; nt < 4; ++nt) {
        bf16x8 bfr = *(const bf16x8*)&Wt[nt * 16 + fr][(ga ^ (fr & 7)) * 8];
        acc[nt] = __builtin_amdgcn_mfma_f32_16x16x32_bf16(af, bfr, acc[nt], 0, 0, 0);
      }
    }
    __syncthreads();
  }

  // ---- epilogue. D: row = wm + fg*4 + r, col = n0 + nt*16 + fr ----
  if (EPI == 0) {
#pragma unroll
    for (int nt = 0; nt < 4; ++nt) {
#pragma unroll
      for (int r = 0; r < 4; ++r) {
        int row = m0 + wm + fg * 4 + r;
        if (row < n) c16[(size_t)row * KOUT + n0 + nt * 16 + fr] = f2bf(acc[nt][r]);
      }
    }
  } else {
    float bv[4];
#pragma unroll
    for (int nt = 0; nt < 4; ++nt) bv[nt] = bias[n0 + nt * 16 + fr];
#pragma unroll
    for (int nt = 0; nt < 4; ++nt) {
#pragma unroll
      for (int r = 0; r < 4; ++r) {
        int row = m0 + wm + fg * 4 + r;
        float v = acc[nt][r] + bv[nt];
        if (EPI == 1) v = v > 0.f ? v : 0.f;
        if (row < n) Cf[(size_t)row * KOUT + n0 + nt * 16 + fr] = v;
      }
    }
  }
  if (ATT) {
    float attsv[4], attdv[4];
#pragma unroll
    for (int nt = 0; nt < 4; ++nt) {
      attsv[nt] = attS[n0 + nt * 16 + fr];
      attdv[nt] = attD[n0 + nt * 16 + fr];
    }
#pragma unroll
    for (int r = 0; r < 4; ++r) {
      float ps = acc[0][r] * attsv[0] + acc[1][r] * attsv[1] +
                 acc[2][r] * attsv[2] + acc[3][r] * attsv[3];
      float pd = acc[0][r] * attdv[0] + acc[1][r] * attdv[1] +
                 acc[2][r] * attdv[2] + acc[3][r] * attdv[3];
#pragma unroll
      for (int o = 1; o < 16; o <<= 1) {
        ps += __shfl_xor(ps, o);
        pd += __shfl_xor(pd, o);
      }
      int row = m0 + wm + fg * 4 + r;
      if (fr == 0 && row < n) {
        a_s[row * NHEAD + blockIdx.y] = ps;
        a_d[row * NHEAD + blockIdx.y] = pd;
      }
    }
  }
}

// ---------------- GCN aggregation, bf16 gather, eighth-wave per edge ----------------
// 8 lanes x uint4 (8 bf16) cover the 128B row; 8 edge slots in flight.
__global__ __launch_bounds__(256) void k_agg16(const unsigned short* __restrict__ P16,
                                               const int* __restrict__ csr_src,
                                               const int* __restrict__ row_ptr,
                                               const float* __restrict__ dinv,
                                               const float* __restrict__ bias,
                                               const float* __restrict__ resid,
                                               float* __restrict__ out, int n) {
  int node = (blockIdx.x * 256 + threadIdx.x) >> 6;
  int lane = threadIdx.x & 63;
  if (node >= n) return;
  int beg = row_ptr[node], end = row_ptr[node + 1];
  int es = lane >> 3;        // edge slot 0..7
  int fo = (lane & 7) * 8;   // 8 feats per lane
  float a[8] = {};
  for (int i = beg + es; i < end; i += 8) {
    int s = csr_src[i];  // uniform within eighth
    float d = dinv[s];
    uint4 v = *(const uint4*)(P16 + (size_t)s * HD + fo);
    a[0] = fmaf(bflo(v.x), d, a[0]); a[1] = fmaf(bfhi(v.x), d, a[1]);
    a[2] = fmaf(bflo(v.y), d, a[2]); a[3] = fmaf(bfhi(v.y), d, a[3]);
    a[4] = fmaf(bflo(v.z), d, a[4]); a[5] = fmaf(bfhi(v.z), d, a[5]);
    a[6] = fmaf(bflo(v.w), d, a[6]); a[7] = fmaf(bfhi(v.w), d, a[7]);
  }
#pragma unroll
  for (int o = 8; o < 64; o <<= 1) {
#pragma unroll
    for (int k = 0; k < 8; ++k) a[k] += __shfl_xor(a[k], o);
  }
  if (lane < 8) {
    float dn = dinv[node];
    float4 b0 = *(const float4*)(bias + fo);
    float4 b1 = *(const float4*)(bias + fo + 4);
    float o0[8];
    o0[0] = a[0] * dn + b0.x; o0[1] = a[1] * dn + b0.y;
    o0[2] = a[2] * dn + b0.z; o0[3] = a[3] * dn + b0.w;
    o0[4] = a[4] * dn + b1.x; o0[5] = a[5] * dn + b1.y;
    o0[6] = a[6] * dn + b1.z; o0[7] = a[7] * dn + b1.w;
#pragma unroll
    for (int k = 0; k < 8; ++k) o0[k] = o0[k] > 0.f ? o0[k] : 0.f;
    if (resid) {
      float4 r0 = *(const float4*)(resid + (size_t)node * HD + fo);
      float4 r1 = *(const float4*)(resid + (size_t)node * HD + fo + 4);
      o0[0] += r0.x; o0[1] += r0.y; o0[2] += r0.z; o0[3] += r0.w;
      o0[4] += r1.x; o0[5] += r1.y; o0[6] += r1.z; o0[7] += r1.w;
    }
    float4 w0; w0.x = o0[0]; w0.y = o0[1]; w0.z = o0[2]; w0.w = o0[3];
    float4 w1; w1.x = o0[4]; w1.y = o0[5]; w1.z = o0[6]; w1.w = o0[7];
    *(float4*)(out + (size_t)node * HD + fo) = w0;
    *(float4*)(out + (size_t)node * HD + fo + 4) = w1;
  }
}

// ---------------- GAT: fused segment softmax + bf16 gather (half-wave P3) ----------------
__device__ __forceinline__ float leaky(float v) { return v > 0.f ? v : 0.2f * v; }

__global__ __launch_bounds__(256) void k_gat(const unsigned short* __restrict__ xg16,
                                             const float* __restrict__ a_s,
                                             const float* __restrict__ a_d,
                                             const int* __restrict__ csr_src,
                                             const int* __restrict__ row_ptr,
                                             float* __restrict__ galpha,  // deg>128 fallback
                                             const float* __restrict__ bg,
                                             float* __restrict__ hg,      // d_out slice (8B-aligned)
                                             float* __restrict__ hga,     // aligned ws copy
                                             int n) {
  __shared__ float4 ew[4][128];
  const int wid = threadIdx.x >> 6;
  const int node = (blockIdx.x * 256 + threadIdx.x) >> 6;
  const int lane = threadIdx.x & 63;
  if (node >= n) return;
  const int beg = row_ptr[node], end = row_ptr[node + 1];
  const bool uselds = (end - beg) <= 128;
  float4 ad = ((const float4*)a_d)[node];

  // P1: logits (registers if uselds), lane-local max
  float m0 = -1e30f, m1 = -1e30f, m2 = -1e30f, m3 = -1e30f;
  float4 e0, e1;
  const int i0 = beg + lane, i1 = beg + lane + 64;
  if (uselds) {
    if (i0 < end) {
      int s = csr_src[i0];
      float4 as = ((const float4*)a_s)[s];
      e0.x = leaky(as.x + ad.x); e0.y = leaky(as.y + ad.y);
      e0.z = leaky(as.z + ad.z); e0.w = leaky(as.w + ad.w);
      m0 = e0.x; m1 = e0.y; m2 = e0.z; m3 = e0.w;
    }
    if (i1 < end) {
      int s = csr_src[i1];
      float4 as = ((const float4*)a_s)[s];
      e1.x = leaky(as.x + ad.x); e1.y = leaky(as.y + ad.y);
      e1.z = leaky(as.z + ad.z); e1.w = leaky(as.w + ad.w);
      m0 = fmaxf(m0, e1.x); m1 = fmaxf(m1, e1.y);
      m2 = fmaxf(m2, e1.z); m3 = fmaxf(m3, e1.w);
    }
  } else {
    for (int i = i0; i < end; i += 64) {
      int s = csr_src[i];
      float4 as = ((const float4*)a_s)[s];
      float4 e;
      e.x = leaky(as.x + ad.x); e.y = leaky(as.y + ad.y);
      e.z = leaky(as.z + ad.z); e.w = leaky(as.w + ad.w);
      ((float4*)galpha)[i] = e;
      m0 = fmaxf(m0, e.x); m1 = fmaxf(m1, e.y);
      m2 = fmaxf(m2, e.z); m3 = fmaxf(m3, e.w);
    }
    __threadfence();
  }
#pragma unroll
  for (int o = 32; o > 0; o >>= 1) {
    m0 = fmaxf(m0, __shfl_xor(m0, o));
    m1 = fmaxf(m1, __shfl_xor(m1, o));
    m2 = fmaxf(m2, __shfl_xor(m2, o));
    m3 = fmaxf(m3, __shfl_xor(m3, o));
  }

  // P2: exp + store + lane-local sum
  float s0 = 0.f, s1 = 0.f, s2 = 0.f, s3 = 0.f;
  if (uselds) {
    if (i0 < end) {
      float4 ex;
      ex.x = expf(e0.x - m0); ex.y = expf(e0.y - m1);
      ex.z = expf(e0.z - m2); ex.w = expf(e0.w - m3);
      ew[wid][i0 - beg] = ex;
      s0 += ex.x; s1 += ex.y; s2 += ex.z; s3 += ex.w;
    }
    if (i1 < end) {
      float4 ex;
      ex.x = expf(e1.x - m0); ex.y = expf(e1.y - m1);
      ex.z = expf(e1.z - m2); ex.w = expf(e1.w - m3);
      ew[wid][i1 - beg] = ex;
      s0 += ex.x; s1 += ex.y; s2 += ex.z; s3 += ex.w;
    }
  } else {
    for (int i = i0; i < end; i += 64) {
      float4 e = ((const float4*)galpha)[i];
      float4 ex;
      ex.x = expf(e.x - m0); ex.y = expf(e.y - m1);
      ex.z = expf(e.z - m2); ex.w = expf(e.w - m3);
      ((float4*)galpha)[i] = ex;
      s0 += ex.x; s1 += ex.y; s2 += ex.z; s3 += ex.w;
    }
    __threadfence();
  }
#pragma unroll
  for (int o = 32; o > 0; o >>= 1) {
    s0 += __shfl_xor(s0, o);
    s1 += __shfl_xor(s1, o);
    s2 += __shfl_xor(s2, o);
    s3 += __shfl_xor(s3, o);
  }
  float r0 = 0.25f / s0, r1 = 0.25f / s1, r2 = 0.25f / s2, r3 = 0.25f / s3;

  // P3: half-wave per edge (32 lanes x uint4 = 512B row), 2-unroll.
  const int hl = lane & 31;       // half-lane: feats hl*8 .. hl*8+7
  const int hw = lane >> 5;       // half id -> edge parity
  const int head = hl >> 3;       // head of this lane's feats
  float a[8] = {}, b[8] = {};

#define GATHER8(ACC, S, AL)                                                     \
  {                                                                             \
    uint4 v = *(const uint4*)(xg16 + (size_t)(S) * 256 + hl * 8);               \
    ACC[0] = fmaf(bflo(v.x), AL, ACC[0]); ACC[1] = fmaf(bfhi(v.x), AL, ACC[1]); \
    ACC[2] = fmaf(bflo(v.y), AL, ACC[2]); ACC[3] = fmaf(bfhi(v.y), AL, ACC[3]); \
    ACC[4] = fmaf(bflo(v.z), AL, ACC[4]); ACC[5] = fmaf(bfhi(v.z), AL, ACC[5]); \
    ACC[6] = fmaf(bflo(v.w), AL, ACC[6]); ACC[7] = fmaf(bfhi(v.w), AL, ACC[7]); \
  }

#define P3_BODY(ALPHA_AT)                                  \
  {                                                        \
    int i = beg + hw;                                      \
    for (; i + 2 < end; i += 4) {                          \
      int sA = csr_src[i], sB = csr_src[i + 2];            \
      float alA = ALPHA_AT(i), alB = ALPHA_AT(i + 2);      \
      GATHER8(a, sA, alA)                                  \
      GATHER8(b, sB, alB)                                  \
    }                                                      \
    for (; i < end; i += 2) {                              \
      int s = csr_src[i];                                  \
      float al = ALPHA_AT(i);                              \
      GATHER8(a, s, al)                                    \
    }                                                      \
  }

  if (uselds) {
    const float* ap = (const float*)&ew[wid][0];
#define AL_LDS(idx) ap[((idx) - beg) * 4 + head]
    P3_BODY(AL_LDS)
#undef AL_LDS
  } else {
#define AL_GBL(idx) galpha[(size_t)(idx) * 4 + head]
    P3_BODY(AL_GBL)
#undef AL_GBL
  }
#undef P3_BODY
#undef GATHER8

  float rh = head == 0 ? r0 : head == 1 ? r1 : head == 2 ? r2 : r3;
  float t[8];
#pragma unroll
  for (int k = 0; k < 8; ++k) {
    t[k] = a[k] + b[k];
    t[k] += __shfl_xor(t[k], 32);  // combine half-waves (same head/feats)
    t[k] *= rh;
    t[k] += __shfl_xor(t[k], 8);   // combine heads
    t[k] += __shfl_xor(t[k], 16);
  }
  if (lane < 8) {
    int f0 = lane * 8;  // feat-in-head offset
    float o0[8];
#pragma unroll
    for (int k = 0; k < 8; ++k) o0[k] = t[k] + bg[f0 + k];
    float4 w0; w0.x = o0[0]; w0.y = o0[1]; w0.z = o0[2]; w0.w = o0[3];
    float4 w1; w1.x = o0[4]; w1.y = o0[5]; w1.z = o0[6]; w1.w = o0[7];
    *(float4*)(hga + (size_t)node * HD + f0) = w0;
    *(float4*)(hga + (size_t)node * HD + f0 + 4) = w1;
    float2 p0; p0.x = o0[0]; p0.y = o0[1];
    float2 p1; p1.x = o0[2]; p1.y = o0[3];
    float2 p2; p2.x = o0[4]; p2.y = o0[5];
    float2 p3; p3.x = o0[6]; p3.y = o0[7];
    *(float2*)(hg + (size_t)node * HD + f0) = p0;
    *(float2*)(hg + (size_t)node * HD + f0 + 2) = p1;
    *(float2*)(hg + (size_t)node * HD + f0 + 4) = p2;
    *(float2*)(hg + (size_t)node * HD + f0 + 6) = p3;
  }
}

// global feature sum of hg -> gsum[64]
__global__ __launch_bounds__(256) void k_gsum(const float* __restrict__ hg,
                                              float* __restrict__ gsum, int n) {
  __shared__ float red[256];
  int f = threadIdx.x & 63, g = threadIdx.x >> 6;
  float local = 0.f;
  for (int nd = blockIdx.x * 4 + g; nd < n; nd += gridDim.x * 4)
    local += hg[(size_t)nd * HD + f];
  red[threadIdx.x] = local;
  __syncthreads();
  if (threadIdx.x < 64)
    atomicAdd(&gsum[f], red[f] + red[64 + f] + red[128 + f] + red[192 + f]);
}

// tiny classifier head
__global__ __launch_bounds__(64) void k_cls(const float* __restrict__ gsum,
                                            const float* __restrict__ Wc1,
                                            const float* __restrict__ bc1,
                                            const float* __restrict__ Wc2,
                                            const float* __restrict__ bc2,
                                            float* __restrict__ out, int n) {
  __shared__ float hgl[64];
  __shared__ float t1[32];
  int t = threadIdx.x;
  hgl[t] = gsum[t] / (float)n;
  __syncthreads();
  if (t < 32) {
    float a = bc1[t];
#pragma unroll 16
    for (int f = 0; f < 64; ++f) a = fmaf(hgl[f], Wc1[f * 32 + t], a);
    t1[t] = a > 0.f ? a : 0.f;
  }
  __syncthreads();
  if (t < 2) {
    float a = bc2[t];
#pragma unroll
    for (int j = 0; j < 32; ++j) a = fmaf(t1[j], Wc2[j * 2 + t], a);
    out[t] = a;
  }
}

extern "C" void kernel_launch(void* const* d_in, const int* in_sizes, int n_in,
                              void* d_out, int out_size, void* d_ws, size_t ws_size,
                              hipStream_t stream) {
  const float* x = (const float*)d_in[0];
  const int* ei = (const int*)d_in[1];
  const float* W0 = (const float*)d_in[2];
  const float* b0 = (const float*)d_in[3];
  const float* W1 = (const float*)d_in[4];
  const float* b1 = (const float*)d_in[5];
  const float* W2 = (const float*)d_in[6];
  const float* b2 = (const float*)d_in[7];
  const float* Wg = (const float*)d_in[8];
  const float* att_src = (const float*)d_in[9];
  const float* att_dst = (const float*)d_in[10];
  const float* bg = (const float*)d_in[11];
  const float* Wc1 = (const float*)d_in[12];
  const float* bc1 = (const float*)d_in[13];
  const float* Wc2 = (const float*)d_in[14];
  const float* bc2 = (const float*)d_in[15];
  const float* Wr1 = (const float*)d_in[16];
  const float* br1 = (const float*)d_in[17];
  const float* Wr2 = (const float*)d_in[18];
  const float* br2 = (const float*)d_in[19];

  const int n = in_sizes[0] / DIN;  // 50000
  const int E = in_sizes[1] / 2;    // 800000
  const int nE = E + n;
  const int* src = ei;
  const int* dst = ei + E;

  // ---- workspace layout ----
  float* ws = (float*)d_ws;
  size_t off = 0;
  auto alloc = [&](size_t nelems) {
    float* p = ws + off;
    off += (nelems + 63) & ~(size_t)63;
    return p;
  };
  int* CNT = (int*)alloc(n);
  int* BSUM = (int*)alloc(256);
  int* BOFF = (int*)alloc(256);
  int* ROWP = (int*)alloc(n + 1);
  int* CURS = (int*)alloc(n);
  int* CSRS = (int*)alloc(nE);
  float* DINV = alloc(n);
  float* P = alloc((size_t)n * 256);                               // f32 scratch (r1)
  unsigned short* XG16 = (unsigned short*)alloc((size_t)n * 128);  // bf16 xg [n,256]
  unsigned short* P16 = (unsigned short*)alloc((size_t)n * 32);    // bf16 P [n,64]
  float* Hb = alloc((size_t)n * HD);                               // hidden h
  float* HG = alloc((size_t)n * HD);                               // aligned copy of hg
  float* ASD = alloc((size_t)n * NHEAD);
  float* ADD = alloc((size_t)n * NHEAD);
  float* GALPHA = alloc((size_t)nE * NHEAD);                       // deg>128 fallback only
  float* GSUM = alloc(64);
  (void)ws_size;

  float* out = (float*)d_out;
  float* out_cls = out;                       // 2
  float* out_rec = out + 2;                   // n*256
  float* out_hg = out + 2 + (size_t)n * 256;  // n*64

  const int TB = 256;
  const int B = cdiv(n, TB);
  const int GM = cdiv(n, 64);  // GEMM M-tiles

  // ---- CSR build (by dst, self-loops included) ----
  k_filli<<<cdiv(n, TB), TB, 0, stream>>>(CNT, 1, n);  // self loop
  k_count<<<cdiv(E, TB), TB, 0, stream>>>(dst, CNT, E);
  k_bsum<<<B, TB, 0, stream>>>(CNT, BSUM, n);
  k_bscan<<<1, TB, 0, stream>>>(BSUM, BOFF, B);
  k_rowptr<<<B, TB, 0, stream>>>(CNT, BOFF, ROWP, CURS, DINV, GSUM, n, nE);
  k_csrfill<<<cdiv(nE, TB), TB, 0, stream>>>(src, dst, CURS, CSRS, E, n);

  // ---- GCN layers (MFMA GEMM -> bf16 message gather) ----
  k_gmfma<256, 64, 0, 0><<<dim3(GM, 1), TB, 0, stream>>>(
      x, W0, P16, n, nullptr, nullptr, nullptr, nullptr, nullptr, nullptr);
  k_agg16<<<cdiv((long)n * 64, TB), TB, 0, stream>>>(P16, CSRS, ROWP, DINV, b0, nullptr, Hb, n);

  k_gmfma<64, 64, 0, 0><<<dim3(GM, 1), TB, 0, stream>>>(
      Hb, W1, P16, n, nullptr, nullptr, nullptr, nullptr, nullptr, nullptr);
  k_agg16<<<cdiv((long)n * 64, TB), TB, 0, stream>>>(P16, CSRS, ROWP, DINV, b1, Hb, Hb, n);

  k_gmfma<64, 64, 0, 0><<<dim3(GM, 1), TB, 0, stream>>>(
      Hb, W2, P16, n, nullptr, nullptr, nullptr, nullptr, nullptr, nullptr);
  k_agg16<<<cdiv((long)n * 64, TB), TB, 0, stream>>>(P16, CSRS, ROWP, DINV, b2, Hb, Hb, n);

  // ---- GAT (att dots fused into MFMA epilogue) ----
  k_gmfma<64, 256, 1, 0><<<dim3(GM, 4), TB, 0, stream>>>(
      Hb, Wg, XG16, n, att_src, att_dst, ASD, ADD, nullptr, nullptr);
  k_gat<<<cdiv((long)n * 64, TB), TB, 0, stream>>>(XG16, ASD, ADD, CSRS, ROWP, GALPHA, bg,
                                                   out_hg, HG, n);

  // ---- global pool + heads (rec path on MFMA too) ----
  k_gsum<<<512, TB, 0, stream>>>(HG, GSUM, n);
  k_cls<<<1, 64, 0, stream>>>(GSUM, Wc1, bc1, Wc2, bc2, out_cls, n);
  k_gmfma<64, 64, 0, 1><<<dim3(GM, 1), TB, 0, stream>>>(
      HG, Wr1, nullptr, n, nullptr, nullptr, nullptr, nullptr, br1, P);
  k_gmfma<64, 256, 0, 2><<<dim3(GM, 4), TB, 0, stream>>>(
      P, Wr2, nullptr, n, nullptr, nullptr, nullptr, nullptr, br2, out_rec);
}

// Round 11
// 340.890 us; speedup vs baseline: 1.6856x; 1.0326x over previous
//
#include <hip/hip_runtime.h>

#define DIN 256
#define HD 64
#define NHEAD 4

static inline int cdiv(long a, long b) { return (int)((a + b - 1) / b); }

typedef __attribute__((ext_vector_type(8))) short bf16x8;
typedef __attribute__((ext_vector_type(4))) float f32x4;

// ---------------- CSR build ----------------
__global__ __launch_bounds__(256) void k_count(const int* __restrict__ dst,
                                               int* __restrict__ cnt, int E) {
  int i = blockIdx.x * 256 + threadIdx.x;
  if (i < E) atomicAdd(&cnt[dst[i]], 1);
}

// block sums of (cnt+1)
__global__ __launch_bounds__(256) void k_bsum(const int* __restrict__ cnt,
                                              int* __restrict__ bsum, int n) {
  __shared__ int sd[256];
  int i = blockIdx.x * 256 + threadIdx.x;
  sd[threadIdx.x] = (i < n) ? cnt[i] + 1 : 0;
  __syncthreads();
  for (int o = 128; o > 0; o >>= 1) {
    if (threadIdx.x < o) sd[threadIdx.x] += sd[threadIdx.x + o];
    __syncthreads();
  }
  if (threadIdx.x == 0) bsum[blockIdx.x] = sd[0];
}

// rowptr (scans bsum inline) + cursor + dinv + GSUM zero
__global__ __launch_bounds__(256) void k_rowptr(const int* __restrict__ cnt,
                                                const int* __restrict__ bsum,
                                                int* __restrict__ row_ptr,
                                                int* __restrict__ cursor,
                                                float* __restrict__ dinv,
                                                float* __restrict__ gsum,
                                                int n, int total, int B) {
  __shared__ int sb[256];
  __shared__ int sd[256];
  int t = threadIdx.x;
  // inclusive scan of block sums
  sb[t] = (t < B) ? bsum[t] : 0;
  __syncthreads();
  for (int o = 1; o < 256; o <<= 1) {
    int x = (t >= o) ? sb[t - o] : 0;
    __syncthreads();
    sb[t] += x;
    __syncthreads();
  }
  int boff = (blockIdx.x > 0) ? sb[blockIdx.x - 1] : 0;
  int i = blockIdx.x * 256 + t;
  int v = (i < n) ? cnt[i] + 1 : 0;
  sd[t] = v;
  __syncthreads();
  for (int o = 1; o < 256; o <<= 1) {
    int x = (t >= o) ? sd[t - o] : 0;
    __syncthreads();
    sd[t] += x;
    __syncthreads();
  }
  if (i < n) {
    int rp = boff + sd[t] - v;
    row_ptr[i] = rp;
    cursor[i] = rp;
    dinv[i] = rsqrtf((float)v);
  }
  if (i == n - 1) row_ptr[n] = total;
  if (blockIdx.x == 0 && t < 64) gsum[t] = 0.f;
}

__global__ __launch_bounds__(256) void k_csrfill(const int* __restrict__ src,
                                                 const int* __restrict__ dst,
                                                 int* __restrict__ cursor,
                                                 int* __restrict__ csr_src, int E, int n) {
  int e = blockIdx.x * 256 + threadIdx.x;
  if (e < E) {
    int pos = atomicAdd(&cursor[dst[e]], 1);
    csr_src[pos] = src[e];
  } else if (e < E + n) {
    int i = e - E;
    int pos = atomicAdd(&cursor[i], 1);
    csr_src[pos] = i;
  }
}

// ---------------- bf16 helpers ----------------
__device__ __forceinline__ unsigned short f2bf(float f) {  // RNE
  unsigned u = __float_as_uint(f);
  u += 0x7FFFu + ((u >> 16) & 1u);
  return (unsigned short)(u >> 16);
}
__device__ __forceinline__ float bflo(unsigned u) { return __uint_as_float(u << 16); }
__device__ __forceinline__ float bfhi(unsigned u) { return __uint_as_float(u & 0xFFFF0000u); }

// ---------------- MFMA GEMM: c16[n,KOUT](bf16) = A[n,KIN](f32) @ W[KIN,KOUT](f32) ----------------
// ATT=1 (KOUT=256): also emit a_s/a_d head-dots (blockIdx.y = head).
template <int KIN, int KOUT, int ATT>
__global__ __launch_bounds__(256, 4) void k_gmfma(const float* __restrict__ A,
                                                  const float* __restrict__ W,
                                                  unsigned short* __restrict__ c16, int n,
                                                  const float* __restrict__ attS,
                                                  const float* __restrict__ attD,
                                                  float* __restrict__ a_s,
                                                  float* __restrict__ a_d) {
  __shared__ unsigned short As[64][64];  // [row][k, granule-swizzled]
  __shared__ unsigned short Wt[64][64];  // [col][k, granule-swizzled]
  const int tid = threadIdx.x;
  const int m0 = blockIdx.x * 64;
  const int n0 = blockIdx.y * 64;
  const int lane = tid & 63;
  const int wid = tid >> 6;
  const int wm = wid * 16;
  const int fr = lane & 15;
  const int fg = lane >> 4;
  f32x4 acc[4] = {{0.f, 0.f, 0.f, 0.f},
                  {0.f, 0.f, 0.f, 0.f},
                  {0.f, 0.f, 0.f, 0.f},
                  {0.f, 0.f, 0.f, 0.f}};

  for (int k0 = 0; k0 < KIN; k0 += 64) {
    {
      int row = tid >> 3;  // 0..31
      int g = tid & 7;
#pragma unroll
      for (int q = 0; q < 2; ++q, row += 32) {
        int gr = m0 + row;
        gr = gr < n ? gr : n - 1;
        const float* ap = A + (size_t)gr * KIN + k0 + g * 8;
        float4 f0 = *(const float4*)ap;
        float4 f1 = *(const float4*)(ap + 4);
        uint4 pk;
        pk.x = (unsigned)f2bf(f0.x) | ((unsigned)f2bf(f0.y) << 16);
        pk.y = (unsigned)f2bf(f0.z) | ((unsigned)f2bf(f0.w) << 16);
        pk.z = (unsigned)f2bf(f1.x) | ((unsigned)f2bf(f1.y) << 16);
        pk.w = (unsigned)f2bf(f1.z) | ((unsigned)f2bf(f1.w) << 16);
        *(uint4*)&As[row][(g ^ (row & 7)) * 8] = pk;
      }
    }
    {
      int col = tid & 63;
      int kb = (tid >> 6) * 16;  // 0,16,32,48
      unsigned pk[8];
#pragma unroll
      for (int i = 0; i < 8; ++i) {
        float lo = W[(size_t)(k0 + kb + 2 * i) * KOUT + n0 + col];
        float hi = W[(size_t)(k0 + kb + 2 * i + 1) * KOUT + n0 + col];
        pk[i] = (unsigned)f2bf(lo) | ((unsigned)f2bf(hi) << 16);
      }
      int g0 = kb >> 3;
      uint4 w0; w0.x = pk[0]; w0.y = pk[1]; w0.z = pk[2]; w0.w = pk[3];
      uint4 w1; w1.x = pk[4]; w1.y = pk[5]; w1.z = pk[6]; w1.w = pk[7];
      *(uint4*)&Wt[col][((g0) ^ (col & 7)) * 8] = w0;
      *(uint4*)&Wt[col][((g0 + 1) ^ (col & 7)) * 8] = w1;
    }
    __syncthreads();
#pragma unroll
    for (int ks = 0; ks < 2; ++ks) {
      int ga = ks * 4 + fg;
      bf16x8 af = *(const bf16x8*)&As[wm + fr][(ga ^ (fr & 7)) * 8];
#pragma unroll
      for (int nt = 0; nt < 4; ++nt) {
        bf16x8 bfr = *(const bf16x8*)&Wt[nt * 16 + fr][(ga ^ (fr & 7)) * 8];
        acc[nt] = __builtin_amdgcn_mfma_f32_16x16x32_bf16(af, bfr, acc[nt], 0, 0, 0);
      }
    }
    __syncthreads();
  }

#pragma unroll
  for (int nt = 0; nt < 4; ++nt) {
#pragma unroll
    for (int r = 0; r < 4; ++r) {
      int row = m0 + wm + fg * 4 + r;
      if (row < n) c16[(size_t)row * KOUT + n0 + nt * 16 + fr] = f2bf(acc[nt][r]);
    }
  }
  if (ATT) {
    float attsv[4], attdv[4];
#pragma unroll
    for (int nt = 0; nt < 4; ++nt) {
      attsv[nt] = attS[n0 + nt * 16 + fr];
      attdv[nt] = attD[n0 + nt * 16 + fr];
    }
#pragma unroll
    for (int r = 0; r < 4; ++r) {
      float ps = acc[0][r] * attsv[0] + acc[1][r] * attsv[1] +
                 acc[2][r] * attsv[2] + acc[3][r] * attsv[3];
      float pd = acc[0][r] * attdv[0] + acc[1][r] * attdv[1] +
                 acc[2][r] * attdv[2] + acc[3][r] * attdv[3];
#pragma unroll
      for (int o = 1; o < 16; o <<= 1) {
        ps += __shfl_xor(ps, o);
        pd += __shfl_xor(pd, o);
      }
      int row = m0 + wm + fg * 4 + r;
      if (fr == 0 && row < n) {
        a_s[row * NHEAD + blockIdx.y] = ps;
        a_d[row * NHEAD + blockIdx.y] = pd;
      }
    }
  }
}

// ---------------- fused rec head: rec = relu(hg@Wr1+br1)@Wr2+br2, + gsum ----------------
__global__ __launch_bounds__(256, 4) void k_rec(const float* __restrict__ hg,  // 8B-aligned
                                                const float* __restrict__ Wr1,
                                                const float* __restrict__ br1,
                                                const float* __restrict__ Wr2,
                                                const float* __restrict__ br2,
                                                float* __restrict__ gsum,
                                                float* __restrict__ rec,  // 8B-aligned
                                                int n) {
  __shared__ unsigned short As[64][64];
  __shared__ unsigned short Ws[64][64];
  __shared__ unsigned short Ts[64][64];
  __shared__ float gs[64];
  const int tid = threadIdx.x;
  const int m0 = blockIdx.x * 64;
  const int lane = tid & 63;
  const int wid = tid >> 6;
  const int wm = wid * 16;
  const int fr = lane & 15, fg = lane >> 4;

  if (tid < 64) gs[tid] = 0.f;
  __syncthreads();

  // stage hg (f32, float2 loads) -> bf16 As; accumulate gsum partials
  {
    int row = tid >> 3, g = tid & 7;
#pragma unroll
    for (int q = 0; q < 2; ++q, row += 32) {
      int gr = m0 + row;
      bool valid = gr < n;
      int cr = valid ? gr : n - 1;
      const float* hp = hg + (size_t)cr * HD + g * 8;
      float2 f0 = *(const float2*)hp;
      float2 f1 = *(const float2*)(hp + 2);
      float2 f2 = *(const float2*)(hp + 4);
      float2 f3 = *(const float2*)(hp + 6);
      uint4 pk;
      pk.x = (unsigned)f2bf(f0.x) | ((unsigned)f2bf(f0.y) << 16);
      pk.y = (unsigned)f2bf(f1.x) | ((unsigned)f2bf(f1.y) << 16);
      pk.z = (unsigned)f2bf(f2.x) | ((unsigned)f2bf(f2.y) << 16);
      pk.w = (unsigned)f2bf(f3.x) | ((unsigned)f2bf(f3.y) << 16);
      *(uint4*)&As[row][(g ^ (row & 7)) * 8] = pk;
      if (valid) {
        atomicAdd(&gs[g * 8 + 0], f0.x); atomicAdd(&gs[g * 8 + 1], f0.y);
        atomicAdd(&gs[g * 8 + 2], f1.x); atomicAdd(&gs[g * 8 + 3], f1.y);
        atomicAdd(&gs[g * 8 + 4], f2.x); atomicAdd(&gs[g * 8 + 5], f2.y);
        atomicAdd(&gs[g * 8 + 6], f3.x); atomicAdd(&gs[g * 8 + 7], f3.y);
      }
    }
  }
  // stage Wr1 -> Ws (transposed, swizzled)
  {
    int col = tid & 63;
    int kb = (tid >> 6) * 16;
    unsigned pk[8];
#pragma unroll
    for (int i = 0; i < 8; ++i) {
      float lo = Wr1[(size_t)(kb + 2 * i) * HD + col];
      float hi = Wr1[(size_t)(kb + 2 * i + 1) * HD + col];
      pk[i] = (unsigned)f2bf(lo) | ((unsigned)f2bf(hi) << 16);
    }
    int g0 = kb >> 3;
    uint4 w0; w0.x = pk[0]; w0.y = pk[1]; w0.z = pk[2]; w0.w = pk[3];
    uint4 w1; w1.x = pk[4]; w1.y = pk[5]; w1.z = pk[6]; w1.w = pk[7];
    *(uint4*)&Ws[col][((g0) ^ (col & 7)) * 8] = w0;
    *(uint4*)&Ws[col][((g0 + 1) ^ (col & 7)) * 8] = w1;
  }
  __syncthreads();
  if (tid < 64) atomicAdd(&gsum[tid], gs[tid]);

  // T = relu(A@Wr1 + br1) -> Ts (bf16, A-layout swizzle)
  {
    f32x4 acc[4] = {{0.f, 0.f, 0.f, 0.f}, {0.f, 0.f, 0.f, 0.f},
                    {0.f, 0.f, 0.f, 0.f}, {0.f, 0.f, 0.f, 0.f}};
#pragma unroll
    for (int ks = 0; ks < 2; ++ks) {
      int ga = ks * 4 + fg;
      bf16x8 af = *(const bf16x8*)&As[wm + fr][(ga ^ (fr & 7)) * 8];
#pragma unroll
      for (int nt = 0; nt < 4; ++nt) {
        bf16x8 bfr = *(const bf16x8*)&Ws[nt * 16 + fr][(ga ^ (fr & 7)) * 8];
        acc[nt] = __builtin_amdgcn_mfma_f32_16x16x32_bf16(af, bfr, acc[nt], 0, 0, 0);
      }
    }
#pragma unroll
    for (int nt = 0; nt < 4; ++nt) {
#pragma unroll
      for (int r = 0; r < 4; ++r) {
        int row = wm + fg * 4 + r;          // local 0..63
        int col = nt * 16 + fr;
        float v = acc[nt][r] + br1[col];
        v = v > 0.f ? v : 0.f;
        Ts[row][(((col >> 3) ^ (row & 7)) * 8) + (col & 7)] = f2bf(v);
      }
    }
  }

  // rec = T @ Wr2 + br2 over 4 column groups (reuse Ws)
  for (int cg = 0; cg < 4; ++cg) {
    __syncthreads();
    {
      int col = tid & 63;
      int kb = (tid >> 6) * 16;
      unsigned pk[8];
#pragma unroll
      for (int i = 0; i < 8; ++i) {
        float lo = Wr2[(size_t)(kb + 2 * i) * 256 + cg * 64 + col];
        float hi = Wr2[(size_t)(kb + 2 * i + 1) * 256 + cg * 64 + col];
        pk[i] = (unsigned)f2bf(lo) | ((unsigned)f2bf(hi) << 16);
      }
      int g0 = kb >> 3;
      uint4 w0; w0.x = pk[0]; w0.y = pk[1]; w0.z = pk[2]; w0.w = pk[3];
      uint4 w1; w1.x = pk[4]; w1.y = pk[5]; w1.z = pk[6]; w1.w = pk[7];
      *(uint4*)&Ws[col][((g0) ^ (col & 7)) * 8] = w0;
      *(uint4*)&Ws[col][((g0 + 1) ^ (col & 7)) * 8] = w1;
    }
    __syncthreads();
    f32x4 acc[4] = {{0.f, 0.f, 0.f, 0.f}, {0.f, 0.f, 0.f, 0.f},
                    {0.f, 0.f, 0.f, 0.f}, {0.f, 0.f, 0.f, 0.f}};
#pragma unroll
    for (int ks = 0; ks < 2; ++ks) {
      int ga = ks * 4 + fg;
      bf16x8 af = *(const bf16x8*)&Ts[wm + fr][(ga ^ (fr & 7)) * 8];
#pragma unroll
      for (int nt = 0; nt < 4; ++nt) {
        bf16x8 bfr = *(const bf16x8*)&Ws[nt * 16 + fr][(ga ^ (fr & 7)) * 8];
        acc[nt] = __builtin_amdgcn_mfma_f32_16x16x32_bf16(af, bfr, acc[nt], 0, 0, 0);
      }
    }
#pragma unroll
    for (int nt = 0; nt < 4; ++nt) {
#pragma unroll
      for (int r = 0; r < 4; ++r) {
        int row = m0 + wm + fg * 4 + r;
        int col = cg * 64 + nt * 16 + fr;
        if (row < n) rec[(size_t)row * 256 + col] = acc[nt][r] + br2[col];
      }
    }
  }
}

// ---------------- GCN aggregation, bf16 gather, eighth-wave per edge ----------------
__global__ __launch_bounds__(256) void k_agg16(const unsigned short* __restrict__ P16,
                                               const int* __restrict__ csr_src,
                                               const int* __restrict__ row_ptr,
                                               const float* __restrict__ dinv,
                                               const float* __restrict__ bias,
                                               const float* __restrict__ resid,
                                               float* __restrict__ out, int n) {
  int node = (blockIdx.x * 256 + threadIdx.x) >> 6;
  int lane = threadIdx.x & 63;
  if (node >= n) return;
  int beg = row_ptr[node], end = row_ptr[node + 1];
  int es = lane >> 3;        // edge slot 0..7
  int fo = (lane & 7) * 8;   // 8 feats per lane
  float a[8] = {};
  for (int i = beg + es; i < end; i += 8) {
    int s = csr_src[i];  // uniform within eighth
    float d = dinv[s];
    uint4 v = *(const uint4*)(P16 + (size_t)s * HD + fo);
    a[0] = fmaf(bflo(v.x), d, a[0]); a[1] = fmaf(bfhi(v.x), d, a[1]);
    a[2] = fmaf(bflo(v.y), d, a[2]); a[3] = fmaf(bfhi(v.y), d, a[3]);
    a[4] = fmaf(bflo(v.z), d, a[4]); a[5] = fmaf(bfhi(v.z), d, a[5]);
    a[6] = fmaf(bflo(v.w), d, a[6]); a[7] = fmaf(bfhi(v.w), d, a[7]);
  }
#pragma unroll
  for (int o = 8; o < 64; o <<= 1) {
#pragma unroll
    for (int k = 0; k < 8; ++k) a[k] += __shfl_xor(a[k], o);
  }
  if (lane < 8) {
    float dn = dinv[node];
    float4 b0 = *(const float4*)(bias + fo);
    float4 b1 = *(const float4*)(bias + fo + 4);
    float o0[8];
    o0[0] = a[0] * dn + b0.x; o0[1] = a[1] * dn + b0.y;
    o0[2] = a[2] * dn + b0.z; o0[3] = a[3] * dn + b0.w;
    o0[4] = a[4] * dn + b1.x; o0[5] = a[5] * dn + b1.y;
    o0[6] = a[6] * dn + b1.z; o0[7] = a[7] * dn + b1.w;
#pragma unroll
    for (int k = 0; k < 8; ++k) o0[k] = o0[k] > 0.f ? o0[k] : 0.f;
    if (resid) {
      float4 r0 = *(const float4*)(resid + (size_t)node * HD + fo);
      float4 r1 = *(const float4*)(resid + (size_t)node * HD + fo + 4);
      o0[0] += r0.x; o0[1] += r0.y; o0[2] += r0.z; o0[3] += r0.w;
      o0[4] += r1.x; o0[5] += r1.y; o0[6] += r1.z; o0[7] += r1.w;
    }
    float4 w0; w0.x = o0[0]; w0.y = o0[1]; w0.z = o0[2]; w0.w = o0[3];
    float4 w1; w1.x = o0[4]; w1.y = o0[5]; w1.z = o0[6]; w1.w = o0[7];
    *(float4*)(out + (size_t)node * HD + fo) = w0;
    *(float4*)(out + (size_t)node * HD + fo + 4) = w1;
  }
}

// ---------------- GAT: fused segment softmax + bf16 gather (half-wave P3) ----------------
__device__ __forceinline__ float leaky(float v) { return v > 0.f ? v : 0.2f * v; }

__global__ __launch_bounds__(256) void k_gat(const unsigned short* __restrict__ xg16,
                                             const float* __restrict__ a_s,
                                             const float* __restrict__ a_d,
                                             const int* __restrict__ csr_src,
                                             const int* __restrict__ row_ptr,
                                             float* __restrict__ galpha,  // deg>128 fallback
                                             const float* __restrict__ bg,
                                             float* __restrict__ hg,      // d_out slice (8B-aligned)
                                             int n) {
  __shared__ float4 ew[4][128];
  const int wid = threadIdx.x >> 6;
  const int node = (blockIdx.x * 256 + threadIdx.x) >> 6;
  const int lane = threadIdx.x & 63;
  if (node >= n) return;
  const int beg = row_ptr[node], end = row_ptr[node + 1];
  const bool uselds = (end - beg) <= 128;
  float4 ad = ((const float4*)a_d)[node];

  // P1: logits (registers if uselds), lane-local max
  float m0 = -1e30f, m1 = -1e30f, m2 = -1e30f, m3 = -1e30f;
  float4 e0, e1;
  const int i0 = beg + lane, i1 = beg + lane + 64;
  if (uselds) {
    if (i0 < end) {
      int s = csr_src[i0];
      float4 as = ((const float4*)a_s)[s];
      e0.x = leaky(as.x + ad.x); e0.y = leaky(as.y + ad.y);
      e0.z = leaky(as.z + ad.z); e0.w = leaky(as.w + ad.w);
      m0 = e0.x; m1 = e0.y; m2 = e0.z; m3 = e0.w;
    }
    if (i1 < end) {
      int s = csr_src[i1];
      float4 as = ((const float4*)a_s)[s];
      e1.x = leaky(as.x + ad.x); e1.y = leaky(as.y + ad.y);
      e1.z = leaky(as.z + ad.z); e1.w = leaky(as.w + ad.w);
      m0 = fmaxf(m0, e1.x); m1 = fmaxf(m1, e1.y);
      m2 = fmaxf(m2, e1.z); m3 = fmaxf(m3, e1.w);
    }
  } else {
    for (int i = i0; i < end; i += 64) {
      int s = csr_src[i];
      float4 as = ((const float4*)a_s)[s];
      float4 e;
      e.x = leaky(as.x + ad.x); e.y = leaky(as.y + ad.y);
      e.z = leaky(as.z + ad.z); e.w = leaky(as.w + ad.w);
      ((float4*)galpha)[i] = e;
      m0 = fmaxf(m0, e.x); m1 = fmaxf(m1, e.y);
      m2 = fmaxf(m2, e.z); m3 = fmaxf(m3, e.w);
    }
    __threadfence();
  }
#pragma unroll
  for (int o = 32; o > 0; o >>= 1) {
    m0 = fmaxf(m0, __shfl_xor(m0, o));
    m1 = fmaxf(m1, __shfl_xor(m1, o));
    m2 = fmaxf(m2, __shfl_xor(m2, o));
    m3 = fmaxf(m3, __shfl_xor(m3, o));
  }

  // P2: exp + store + lane-local sum
  float s0 = 0.f, s1 = 0.f, s2 = 0.f, s3 = 0.f;
  if (uselds) {
    if (i0 < end) {
      float4 ex;
      ex.x = expf(e0.x - m0); ex.y = expf(e0.y - m1);
      ex.z = expf(e0.z - m2); ex.w = expf(e0.w - m3);
      ew[wid][i0 - beg] = ex;
      s0 += ex.x; s1 += ex.y; s2 += ex.z; s3 += ex.w;
    }
    if (i1 < end) {
      float4 ex;
      ex.x = expf(e1.x - m0); ex.y = expf(e1.y - m1);
      ex.z = expf(e1.z - m2); ex.w = expf(e1.w - m3);
      ew[wid][i1 - beg] = ex;
      s0 += ex.x; s1 += ex.y; s2 += ex.z; s3 += ex.w;
    }
  } else {
    for (int i = i0; i < end; i += 64) {
      float4 e = ((const float4*)galpha)[i];
      float4 ex;
      ex.x = expf(e.x - m0); ex.y = expf(e.y - m1);
      ex.z = expf(e.z - m2); ex.w = expf(e.w - m3);
      ((float4*)galpha)[i] = ex;
      s0 += ex.x; s1 += ex.y; s2 += ex.z; s3 += ex.w;
    }
    __threadfence();
  }
#pragma unroll
  for (int o = 32; o > 0; o >>= 1) {
    s0 += __shfl_xor(s0, o);
    s1 += __shfl_xor(s1, o);
    s2 += __shfl_xor(s2, o);
    s3 += __shfl_xor(s3, o);
  }
  float r0 = 0.25f / s0, r1 = 0.25f / s1, r2 = 0.25f / s2, r3 = 0.25f / s3;

  // P3: half-wave per edge (32 lanes x uint4 = 512B row), 2-unroll.
  const int hl = lane & 31;
  const int hw = lane >> 5;
  const int head = hl >> 3;
  float a[8] = {}, b[8] = {};

#define GATHER8(ACC, S, AL)                                                     \
  {                                                                             \
    uint4 v = *(const uint4*)(xg16 + (size_t)(S) * 256 + hl * 8);               \
    ACC[0] = fmaf(bflo(v.x), AL, ACC[0]); ACC[1] = fmaf(bfhi(v.x), AL, ACC[1]); \
    ACC[2] = fmaf(bflo(v.y), AL, ACC[2]); ACC[3] = fmaf(bfhi(v.y), AL, ACC[3]); \
    ACC[4] = fmaf(bflo(v.z), AL, ACC[4]); ACC[5] = fmaf(bfhi(v.z), AL, ACC[5]); \
    ACC[6] = fmaf(bflo(v.w), AL, ACC[6]); ACC[7] = fmaf(bfhi(v.w), AL, ACC[7]); \
  }

#define P3_BODY(ALPHA_AT)                                  \
  {                                                        \
    int i = beg + hw;                                      \
    for (; i + 2 < end; i += 4) {                          \
      int sA = csr_src[i], sB = csr_src[i + 2];            \
      float alA = ALPHA_AT(i), alB = ALPHA_AT(i + 2);      \
      GATHER8(a, sA, alA)                                  \
      GATHER8(b, sB, alB)                                  \
    }                                                      \
    for (; i < end; i += 2) {                              \
      int s = csr_src[i];                                  \
      float al = ALPHA_AT(i);                              \
      GATHER8(a, s, al)                                    \
    }                                                      \
  }

  if (uselds) {
    const float* ap = (const float*)&ew[wid][0];
#define AL_LDS(idx) ap[((idx) - beg) * 4 + head]
    P3_BODY(AL_LDS)
#undef AL_LDS
  } else {
#define AL_GBL(idx) galpha[(size_t)(idx) * 4 + head]
    P3_BODY(AL_GBL)
#undef AL_GBL
  }
#undef P3_BODY
#undef GATHER8

  float rh = head == 0 ? r0 : head == 1 ? r1 : head == 2 ? r2 : r3;
  float t[8];
#pragma unroll
  for (int k = 0; k < 8; ++k) {
    t[k] = a[k] + b[k];
    t[k] += __shfl_xor(t[k], 32);  // combine half-waves
    t[k] *= rh;
    t[k] += __shfl_xor(t[k], 8);   // combine heads
    t[k] += __shfl_xor(t[k], 16);
  }
  if (lane < 8) {
    int f0 = lane * 8;
    float o0[8];
#pragma unroll
    for (int k = 0; k < 8; ++k) o0[k] = t[k] + bg[f0 + k];
    float2 p0; p0.x = o0[0]; p0.y = o0[1];
    float2 p1; p1.x = o0[2]; p1.y = o0[3];
    float2 p2; p2.x = o0[4]; p2.y = o0[5];
    float2 p3; p3.x = o0[6]; p3.y = o0[7];
    *(float2*)(hg + (size_t)node * HD + f0) = p0;
    *(float2*)(hg + (size_t)node * HD + f0 + 2) = p1;
    *(float2*)(hg + (size_t)node * HD + f0 + 4) = p2;
    *(float2*)(hg + (size_t)node * HD + f0 + 6) = p3;
  }
}

// tiny classifier head
__global__ __launch_bounds__(64) void k_cls(const float* __restrict__ gsum,
                                            const float* __restrict__ Wc1,
                                            const float* __restrict__ bc1,
                                            const float* __restrict__ Wc2,
                                            const float* __restrict__ bc2,
                                            float* __restrict__ out, int n) {
  __shared__ float hgl[64];
  __shared__ float t1[32];
  int t = threadIdx.x;
  hgl[t] = gsum[t] / (float)n;
  __syncthreads();
  if (t < 32) {
    float a = bc1[t];
#pragma unroll 16
    for (int f = 0; f < 64; ++f) a = fmaf(hgl[f], Wc1[f * 32 + t], a);
    t1[t] = a > 0.f ? a : 0.f;
  }
  __syncthreads();
  if (t < 2) {
    float a = bc2[t];
#pragma unroll
    for (int j = 0; j < 32; ++j) a = fmaf(t1[j], Wc2[j * 2 + t], a);
    out[t] = a;
  }
}

extern "C" void kernel_launch(void* const* d_in, const int* in_sizes, int n_in,
                              void* d_out, int out_size, void* d_ws, size_t ws_size,
                              hipStream_t stream) {
  const float* x = (const float*)d_in[0];
  const int* ei = (const int*)d_in[1];
  const float* W0 = (const float*)d_in[2];
  const float* b0 = (const float*)d_in[3];
  const float* W1 = (const float*)d_in[4];
  const float* b1 = (const float*)d_in[5];
  const float* W2 = (const float*)d_in[6];
  const float* b2 = (const float*)d_in[7];
  const float* Wg = (const float*)d_in[8];
  const float* att_src = (const float*)d_in[9];
  const float* att_dst = (const float*)d_in[10];
  const float* bg = (const float*)d_in[11];
  const float* Wc1 = (const float*)d_in[12];
  const float* bc1 = (const float*)d_in[13];
  const float* Wc2 = (const float*)d_in[14];
  const float* bc2 = (const float*)d_in[15];
  const float* Wr1 = (const float*)d_in[16];
  const float* br1 = (const float*)d_in[17];
  const float* Wr2 = (const float*)d_in[18];
  const float* br2 = (const float*)d_in[19];

  const int n = in_sizes[0] / DIN;  // 50000
  const int E = in_sizes[1] / 2;    // 800000
  const int nE = E + n;
  const int* src = ei;
  const int* dst = ei + E;

  // ---- workspace layout ----
  float* ws = (float*)d_ws;
  size_t off = 0;
  auto alloc = [&](size_t nelems) {
    float* p = ws + off;
    off += (nelems + 63) & ~(size_t)63;
    return p;
  };
  int* CNT = (int*)alloc(n);
  int* BSUM = (int*)alloc(256);
  int* ROWP = (int*)alloc(n + 1);
  int* CURS = (int*)alloc(n);
  int* CSRS = (int*)alloc(nE);
  float* DINV = alloc(n);
  unsigned short* XG16 = (unsigned short*)alloc((size_t)n * 128);  // bf16 xg [n,256]
  unsigned short* P16 = (unsigned short*)alloc((size_t)n * 32);    // bf16 P [n,64]
  float* Hb = alloc((size_t)n * HD);                               // hidden h
  float* ASD = alloc((size_t)n * NHEAD);
  float* ADD = alloc((size_t)n * NHEAD);
  float* GALPHA = alloc((size_t)nE * NHEAD);                       // deg>128 fallback only
  float* GSUM = alloc(64);
  (void)ws_size;

  float* out = (float*)d_out;
  float* out_cls = out;                       // 2
  float* out_rec = out + 2;                   // n*256
  float* out_hg = out + 2 + (size_t)n * 256;  // n*64

  const int TB = 256;
  const int B = cdiv(n, TB);
  const int GM = cdiv(n, 64);  // GEMM M-tiles

  // ---- CSR build (by dst, self-loops as cnt+1) ----
  hipMemsetAsync(CNT, 0, (size_t)n * sizeof(int), stream);
  k_count<<<cdiv(E, TB), TB, 0, stream>>>(dst, CNT, E);
  k_bsum<<<B, TB, 0, stream>>>(CNT, BSUM, n);
  k_rowptr<<<B, TB, 0, stream>>>(CNT, BSUM, ROWP, CURS, DINV, GSUM, n, nE, B);
  k_csrfill<<<cdiv(nE, TB), TB, 0, stream>>>(src, dst, CURS, CSRS, E, n);

  // ---- GCN layers (MFMA GEMM -> bf16 message gather) ----
  k_gmfma<256, 64, 0><<<dim3(GM, 1), TB, 0, stream>>>(x, W0, P16, n,
                                                      nullptr, nullptr, nullptr, nullptr);
  k_agg16<<<cdiv((long)n * 64, TB), TB, 0, stream>>>(P16, CSRS, ROWP, DINV, b0, nullptr, Hb, n);

  k_gmfma<64, 64, 0><<<dim3(GM, 1), TB, 0, stream>>>(Hb, W1, P16, n,
                                                     nullptr, nullptr, nullptr, nullptr);
  k_agg16<<<cdiv((long)n * 64, TB), TB, 0, stream>>>(P16, CSRS, ROWP, DINV, b1, Hb, Hb, n);

  k_gmfma<64, 64, 0><<<dim3(GM, 1), TB, 0, stream>>>(Hb, W2, P16, n,
                                                     nullptr, nullptr, nullptr, nullptr);
  k_agg16<<<cdiv((long)n * 64, TB), TB, 0, stream>>>(P16, CSRS, ROWP, DINV, b2, Hb, Hb, n);

  // ---- GAT (att dots fused into MFMA epilogue) ----
  k_gmfma<64, 256, 1><<<dim3(GM, 4), TB, 0, stream>>>(Hb, Wg, XG16, n,
                                                      att_src, att_dst, ASD, ADD);
  k_gat<<<cdiv((long)n * 64, TB), TB, 0, stream>>>(XG16, ASD, ADD, CSRS, ROWP, GALPHA, bg,
                                                   out_hg, n);

  // ---- heads: fused rec (+gsum), then classifier ----
  k_rec<<<GM, TB, 0, stream>>>(out_hg, Wr1, br1, Wr2, br2, GSUM, out_rec, n);
  k_cls<<<1, 64, 0, stream>>>(GSUM, Wc1, bc1, Wc2, bc2, out_cls, n);
}